// Round 6
// baseline (406.899 us; speedup 1.0000x reference)
//
#include <hip/hip_runtime.h>

#define EMB  1024
#define VIN  512
#define VOUT 1024
#define NH   16
#define DH   64
#define BB   8
#define LQ   512
#define LK   1024

typedef __attribute__((ext_vector_type(8))) short bf16x8;
typedef __attribute__((ext_vector_type(4))) float f32x4;

typedef const __attribute__((address_space(1))) unsigned int* gptr_t;
typedef __attribute__((address_space(3))) unsigned int* lptr_t;

__device__ __forceinline__ unsigned short f2bf(float x) {
    unsigned int u = __float_as_uint(x);
    u += 0x7FFF + ((u >> 16) & 1);   // RN-even
    return (unsigned short)(u >> 16);
}
__device__ __forceinline__ float bf2f(unsigned short h) {
    return __uint_as_float(((unsigned int)h) << 16);
}

#define SWZ(row, cb) (((row) << 7) + ((cb) ^ (((row) & 7) << 4)))

// ---------------------------------------------------------------------------
// Elementwise fp32 -> bf16 hi/lo planes (A pre-split). 4M elems per input.
// ---------------------------------------------------------------------------
__global__ __launch_bounds__(256) void asplit(const float* __restrict__ in,
                                              unsigned short* __restrict__ ph,
                                              unsigned short* __restrict__ pl)
{
    const int i = blockIdx.x * 256 + threadIdx.x;   // 1M threads x 4 elems
    float v[4];
    *reinterpret_cast<float4*>(v) = *reinterpret_cast<const float4*>(&in[(size_t)i * 4]);
    unsigned short h[4], l[4];
#pragma unroll
    for (int j = 0; j < 4; ++j) {
        h[j] = f2bf(v[j]);
        l[j] = f2bf(v[j] - bf2f(h[j]));
    }
    *reinterpret_cast<uint2*>(&ph[(size_t)i * 4]) = *reinterpret_cast<uint2*>(h);
    *reinterpret_cast<uint2*>(&pl[(size_t)i * 4]) = *reinterpret_cast<uint2*>(l);
}

// ---------------------------------------------------------------------------
// W [K,N] fp32 -> Wht, Wlt [N,K] bf16 hi/lo planes (transposed split).
// ---------------------------------------------------------------------------
__global__ __launch_bounds__(256) void wsplit_t(const float* __restrict__ W,
                                                unsigned short* __restrict__ Wht,
                                                unsigned short* __restrict__ Wlt,
                                                int K, int N)
{
    __shared__ float t[32][33];
    const int n0 = blockIdx.x * 32, k0 = blockIdx.y * 32;
    const int tx = threadIdx.x, ty = threadIdx.y;  // 32 x 8
#pragma unroll
    for (int r = 0; r < 32; r += 8)
        t[ty + r][tx] = W[(size_t)(k0 + ty + r) * N + n0 + tx];
    __syncthreads();
#pragma unroll
    for (int r = 0; r < 32; r += 8) {
        float x = t[tx][ty + r];
        unsigned short h = f2bf(x);
        unsigned short l = f2bf(x - bf2f(h));
        size_t o = (size_t)(n0 + ty + r) * K + k0 + tx;
        Wht[o] = h;
        Wlt[o] = l;
    }
}

// ---------------------------------------------------------------------------
// Split-bf16 MFMA GEMM, A pre-split: C = A @ W + bias (3-product split).
// A given as bf16 hi/lo planes [M,K]; W as transposed planes [N,K].
// EPI=0: fp32 C.  EPI=1: bf16 hi plane only, natural.  EPI=2: hi plane
// transposed per head: [(row/1024)*NH + col/64][col%64][row%1024].
// ---------------------------------------------------------------------------
template<int EPI>
__global__ __launch_bounds__(256, 2) void gemm2(const unsigned short* __restrict__ Ah,
                                                const unsigned short* __restrict__ Al,
                                                const unsigned short* __restrict__ Bht,
                                                const unsigned short* __restrict__ Blt,
                                                const float* __restrict__ bias,
                                                float* __restrict__ C,
                                                unsigned short* __restrict__ Ch,
                                                int M, int N, int K)
{
    __shared__ unsigned short As_h[128 * 64], As_l[128 * 64];
    __shared__ unsigned short Bs_h[128 * 64], Bs_l[128 * 64];

    const int nbx = N >> 7;
    const int nwg = gridDim.x;
    const int qq  = nwg >> 3;
    const int id  = blockIdx.x;
    const int swz = (id & 7) * qq + (id >> 3);   // XCD-aware (nwg % 8 == 0)
    const int bx = swz % nbx, by = swz / nbx;
    const int m0 = by * 128, n0 = bx * 128;

    const int tid  = threadIdx.x;
    const int lane = tid & 63;
    const int wid  = tid >> 6;
    const int wm = (wid & 1) * 64;
    const int wn = (wid >> 1) * 64;
    const int lr = lane & 15;
    const int lk = lane >> 4;

    f32x4 acc[4][4];
#pragma unroll
    for (int i = 0; i < 4; ++i)
#pragma unroll
        for (int j = 0; j < 4; ++j) acc[i][j] = (f32x4)(0.f);

    int4 asth[4], astl[4], bsth[4], bstl[4];
    const int nt = K >> 6;

    {
#pragma unroll
        for (int r = 0; r < 4; ++r) {
            int i = r * 256 + tid, row = i >> 3, c16 = i & 7;
            size_t oa = (size_t)(m0 + row) * K + c16 * 8;
            asth[r] = *reinterpret_cast<const int4*>(&Ah[oa]);
            astl[r] = *reinterpret_cast<const int4*>(&Al[oa]);
            size_t ob = (size_t)(n0 + row) * K + c16 * 8;
            bsth[r] = *reinterpret_cast<const int4*>(&Bht[ob]);
            bstl[r] = *reinterpret_cast<const int4*>(&Blt[ob]);
        }
    }

    for (int t = 0; t < nt; ++t) {
        __syncthreads();
#pragma unroll
        for (int r = 0; r < 4; ++r) {
            int i = r * 256 + tid, row = i >> 3, c16 = i & 7;
            int off = SWZ(row, c16 * 16);
            *reinterpret_cast<int4*>((char*)As_h + off) = asth[r];
            *reinterpret_cast<int4*>((char*)As_l + off) = astl[r];
            *reinterpret_cast<int4*>((char*)Bs_h + off) = bsth[r];
            *reinterpret_cast<int4*>((char*)Bs_l + off) = bstl[r];
        }
        __syncthreads();

        if (t + 1 < nt) {
            const int k0 = (t + 1) << 6;
#pragma unroll
            for (int r = 0; r < 4; ++r) {
                int i = r * 256 + tid, row = i >> 3, c16 = i & 7;
                size_t oa = (size_t)(m0 + row) * K + k0 + c16 * 8;
                asth[r] = *reinterpret_cast<const int4*>(&Ah[oa]);
                astl[r] = *reinterpret_cast<const int4*>(&Al[oa]);
                size_t ob = (size_t)(n0 + row) * K + k0 + c16 * 8;
                bsth[r] = *reinterpret_cast<const int4*>(&Bht[ob]);
                bstl[r] = *reinterpret_cast<const int4*>(&Blt[ob]);
            }
        }

#pragma unroll
        for (int ks = 0; ks < 2; ++ks) {
            bf16x8 ah[4], al[4], bh[4], bl[4];
            const int cb = ks * 64 + lk * 16;
#pragma unroll
            for (int f = 0; f < 4; ++f) {
                int rowA = wm + f * 16 + lr;
                ah[f] = *reinterpret_cast<const bf16x8*>((char*)As_h + SWZ(rowA, cb));
                al[f] = *reinterpret_cast<const bf16x8*>((char*)As_l + SWZ(rowA, cb));
                int rowB = wn + f * 16 + lr;
                bh[f] = *reinterpret_cast<const bf16x8*>((char*)Bs_h + SWZ(rowB, cb));
                bl[f] = *reinterpret_cast<const bf16x8*>((char*)Bs_l + SWZ(rowB, cb));
            }
#pragma unroll
            for (int fm = 0; fm < 4; ++fm)
#pragma unroll
                for (int fn = 0; fn < 4; ++fn) {
                    acc[fm][fn] = __builtin_amdgcn_mfma_f32_16x16x32_bf16(ah[fm], bh[fn], acc[fm][fn], 0, 0, 0);
                    acc[fm][fn] = __builtin_amdgcn_mfma_f32_16x16x32_bf16(ah[fm], bl[fn], acc[fm][fn], 0, 0, 0);
                    acc[fm][fn] = __builtin_amdgcn_mfma_f32_16x16x32_bf16(al[fm], bh[fn], acc[fm][fn], 0, 0, 0);
                }
        }
    }

#pragma unroll
    for (int fn = 0; fn < 4; ++fn) {
        const int col = n0 + wn + fn * 16 + lr;
        const float bv = bias[col];
#pragma unroll
        for (int fm = 0; fm < 4; ++fm) {
            const int row0 = m0 + wm + fm * 16 + lk * 4;
            if constexpr (EPI == 0) {
#pragma unroll
                for (int r = 0; r < 4; ++r)
                    C[(size_t)(row0 + r) * N + col] = acc[fm][fn][r] + bv;
            } else if constexpr (EPI == 1) {
#pragma unroll
                for (int r = 0; r < 4; ++r)
                    Ch[(size_t)(row0 + r) * N + col] = f2bf(acc[fm][fn][r] + bv);
            } else {
                unsigned short h4[4];
#pragma unroll
                for (int r = 0; r < 4; ++r)
                    h4[r] = f2bf(acc[fm][fn][r] + bv);
                size_t o = (((size_t)((row0 >> 10) * NH + (col >> 6)) * 64 + (col & 63)) << 10) + (row0 & 1023);
                *reinterpret_cast<uint2*>(&Ch[o]) = *reinterpret_cast<uint2*>(h4);
            }
        }
    }
}

// ---------------------------------------------------------------------------
// Stage 32 rows x 128B (row stride 1024 elems) into linear LDS, source
// pre-swizzled so SWZ reads land correctly. One wave, 4 x 16B per lane.
// ---------------------------------------------------------------------------
__device__ __forceinline__ void stage32(const unsigned short* g0, unsigned short* l0, int lane)
{
#pragma unroll
    for (int r = 0; r < 4; ++r) {
        int row  = r * 8 + (lane >> 3);
        int colb = ((lane & 7) << 4) ^ ((row & 7) << 4);
        const unsigned short* src = g0 + ((size_t)row << 10) + (colb >> 1);
        __builtin_amdgcn_global_load_lds((gptr_t)src, (lptr_t)(l0 + r * 512), 16, 0, 0);
    }
}

// ---------------------------------------------------------------------------
// MFMA flash attention, plain bf16 inputs (noise washed by softmax + Wo).
// K plane [8192,1024]; Vt plane [(b*NH+h)*64 + dv][key]. Writes ctx as
// split hi/lo bf16 planes [4096,1024] (A-operand of the O-projection).
// 1-D grid, XCD-grouped decode. 40KB LDS -> 4 blocks/CU.
// ---------------------------------------------------------------------------
__global__ __launch_bounds__(256, 4) void attn_mfma(const float* __restrict__ Qp,
                                                    const unsigned short* __restrict__ Kh,
                                                    const unsigned short* __restrict__ Vth,
                                                    unsigned short* __restrict__ Ch,
                                                    unsigned short* __restrict__ Cl)
{
    const int id  = blockIdx.x;
    const int qt  = (id >> 3) & 7;
    const int grp = (id & 7) | ((id >> 6) << 3);   // 0..127, same-XCD groups
    const int h = grp & 15, b = grp >> 4;

    const int tid  = threadIdx.x;
    const int lane = tid & 63;
    const int w    = tid >> 6;
    const int lr   = lane & 15;
    const int lk   = lane >> 4;

    __shared__ unsigned short KVs[2][2][4096];   // [buf][K,Vt][64x64]
    __shared__ unsigned short Ps[4][1024];       // per-wave P [q16][key64]

    // Q fragments (scaled bf16), rows w*16 + lr
    bf16x8 qb[2];
    {
        const float scale = 0.125f;  // 1/sqrt(64)
        const float* qrow = &Qp[(size_t)(b * LQ + qt * 64 + w * 16 + lr) * EMB + h * DH];
#pragma unroll
        for (int ks = 0; ks < 2; ++ks) {
            float v[8];
            *reinterpret_cast<float4*>(v)     = *reinterpret_cast<const float4*>(&qrow[ks * 32 + lk * 8]);
            *reinterpret_cast<float4*>(v + 4) = *reinterpret_cast<const float4*>(&qrow[ks * 32 + lk * 8 + 4]);
            unsigned short hh[8];
#pragma unroll
            for (int e = 0; e < 8; ++e) hh[e] = f2bf(v[e] * scale);
            qb[ks] = *reinterpret_cast<bf16x8*>(hh);
        }
    }

    const unsigned short* K0 = Kh + ((size_t)(b * LK) << 10) + h * DH;
    const unsigned short* V0 = Vth + ((size_t)(grp * 64) << 10);

    // prefetch tile 0: waves 0,1 -> K rows 0-31/32-63; waves 2,3 -> Vt
    {
        const int half = (w & 1) * 32;
        if (w < 2) stage32(K0 + ((size_t)half << 10), KVs[0][0] + half * 64, lane);
        else       stage32(V0 + ((size_t)half << 10), KVs[0][1] + half * 64, lane);
    }

    float m[4], lsum[4];
    f32x4 acc[4];
#pragma unroll
    for (int r = 0; r < 4; ++r) { m[r] = -1e30f; lsum[r] = 0.f; }
#pragma unroll
    for (int f = 0; f < 4; ++f) acc[f] = (f32x4)(0.f);

    for (int kt = 0; kt < LK / 64; ++kt) {
        const int cur = kt & 1;
        __syncthreads();   // vmcnt drained: tile kt resident; prev compute done

        if (kt + 1 < LK / 64) {
            const size_t koff = (size_t)(kt + 1) * 64;
            const int half = (w & 1) * 32;
            if (w < 2) stage32(K0 + ((koff + half) << 10), KVs[cur ^ 1][0] + half * 64, lane);
            else       stage32(V0 + ((size_t)half << 10) + koff, KVs[cur ^ 1][1] + half * 64, lane);
        }

        const char* Ks = (const char*)KVs[cur][0];
        const char* Vs = (const char*)KVs[cur][1];

        // QK^T
        f32x4 s[4];
#pragma unroll
        for (int fn = 0; fn < 4; ++fn) s[fn] = (f32x4)(0.f);
#pragma unroll
        for (int ks = 0; ks < 2; ++ks) {
            const int cb = ks * 64 + lk * 16;
#pragma unroll
            for (int fn = 0; fn < 4; ++fn) {
                bf16x8 kb = *reinterpret_cast<const bf16x8*>(Ks + SWZ(fn * 16 + lr, cb));
                s[fn] = __builtin_amdgcn_mfma_f32_16x16x32_bf16(qb[ks], kb, s[fn], 0, 0, 0);
            }
        }

        // online softmax (rows lk*4 + r)
#pragma unroll
        for (int r = 0; r < 4; ++r) {
            float mx = fmaxf(fmaxf(s[0][r], s[1][r]), fmaxf(s[2][r], s[3][r]));
            mx = fmaxf(mx, __shfl_xor(mx, 1));
            mx = fmaxf(mx, __shfl_xor(mx, 2));
            mx = fmaxf(mx, __shfl_xor(mx, 4));
            mx = fmaxf(mx, __shfl_xor(mx, 8));
            float mnew = fmaxf(m[r], mx);
            float corr = __expf(m[r] - mnew);
            m[r] = mnew;
            float rs = 0.f;
#pragma unroll
            for (int fn = 0; fn < 4; ++fn) {
                float p = __expf(s[fn][r] - mnew);
                s[fn][r] = p;
                rs += p;
            }
            rs += __shfl_xor(rs, 1);
            rs += __shfl_xor(rs, 2);
            rs += __shfl_xor(rs, 4);
            rs += __shfl_xor(rs, 8);
            lsum[r] = lsum[r] * corr + rs;
#pragma unroll
            for (int f = 0; f < 4; ++f) acc[f][r] *= corr;
        }

        // P (bf16) -> wave-private LDS [q][key]
#pragma unroll
        for (int fn = 0; fn < 4; ++fn)
#pragma unroll
            for (int r = 0; r < 4; ++r) {
                int q = lk * 4 + r, cb = 2 * (fn * 16 + lr);
                *reinterpret_cast<unsigned short*>((char*)Ps[w] + SWZ(q, cb)) = f2bf(s[fn][r]);
            }

        // PV
#pragma unroll
        for (int ks = 0; ks < 2; ++ks) {
            const int cb = ks * 64 + lk * 16;
            bf16x8 pa = *reinterpret_cast<const bf16x8*>((char*)Ps[w] + SWZ(lr, cb));
#pragma unroll
            for (int f = 0; f < 4; ++f) {
                bf16x8 vb = *reinterpret_cast<const bf16x8*>(Vs + SWZ(f * 16 + lr, cb));
                acc[f] = __builtin_amdgcn_mfma_f32_16x16x32_bf16(pa, vb, acc[f], 0, 0, 0);
            }
        }
    }

    // epilogue: normalize, split, write ctx hi/lo planes
#pragma unroll
    for (int r = 0; r < 4; ++r) {
        float inv = 1.f / lsum[r];
        const size_t row = (size_t)(b * LQ + qt * 64 + w * 16 + lk * 4 + r);
#pragma unroll
        for (int f = 0; f < 4; ++f) {
            float x = acc[f][r] * inv;
            unsigned short hh = f2bf(x);
            size_t o = (row << 10) + h * DH + f * 16 + lr;
            Ch[o] = hh;
            Cl[o] = f2bf(x - bf2f(hh));
        }
    }
}

extern "C" void kernel_launch(void* const* d_in, const int* in_sizes, int n_in,
                              void* d_out, int out_size, void* d_ws, size_t ws_size,
                              hipStream_t stream)
{
    const float* query = (const float*)d_in[0];
    const float* key   = (const float*)d_in[1];
    const float* value = (const float*)d_in[2];
    const float* Wq = (const float*)d_in[3];
    const float* bq = (const float*)d_in[4];
    const float* Wk = (const float*)d_in[5];
    const float* bk = (const float*)d_in[6];
    const float* Wv = (const float*)d_in[7];
    const float* bv = (const float*)d_in[8];
    const float* Wo = (const float*)d_in[9];
    const float* bo = (const float*)d_in[10];
    float* out = (float*)d_out;

    // ws (84MB): Qp16 | Kh16 | Vth16 | Ah8 | Al8 | Ch8 | Cl8 | Wht2 | Wlt2
    float* Qp = (float*)d_ws;
    unsigned short* Kh  = (unsigned short*)(Qp + (size_t)BB * LQ * EMB);
    unsigned short* Vth = Kh  + (size_t)BB * LK * EMB;
    unsigned short* Ah  = Vth + (size_t)BB * LK * VOUT;
    unsigned short* Al  = Ah  + (size_t)4194304;
    unsigned short* Ch  = Al  + (size_t)4194304;
    unsigned short* Cl  = Ch  + (size_t)4194304;
    unsigned short* Wht = Cl  + (size_t)4194304;
    unsigned short* Wlt = Wht + (size_t)EMB * EMB;

    // Q projection
    asplit<<<4096, 256, 0, stream>>>(query, Ah, Al);
    wsplit_t<<<dim3(EMB / 32, EMB / 32), dim3(32, 8), 0, stream>>>(Wq, Wht, Wlt, EMB, EMB);
    gemm2<0><<<(EMB / 128) * (BB * LQ / 128), 256, 0, stream>>>(Ah, Al, Wht, Wlt, bq, Qp, nullptr, BB * LQ, EMB, EMB);

    // K projection -> bf16 plane
    asplit<<<4096, 256, 0, stream>>>(key, Ah, Al);
    wsplit_t<<<dim3(EMB / 32, VIN / 32), dim3(32, 8), 0, stream>>>(Wk, Wht, Wlt, VIN, EMB);
    gemm2<1><<<(EMB / 128) * (BB * LK / 128), 256, 0, stream>>>(Ah, Al, Wht, Wlt, bk, nullptr, Kh, BB * LK, EMB, VIN);

    // V projection -> transposed bf16 plane
    asplit<<<4096, 256, 0, stream>>>(value, Ah, Al);
    wsplit_t<<<dim3(VOUT / 32, VIN / 32), dim3(32, 8), 0, stream>>>(Wv, Wht, Wlt, VIN, VOUT);
    gemm2<2><<<(VOUT / 128) * (BB * LK / 128), 256, 0, stream>>>(Ah, Al, Wht, Wlt, bv, nullptr, Vth, BB * LK, VOUT, VIN);

    // Attention -> ctx split planes
    attn_mfma<<<LQ / 64 * NH * BB, 256, 0, stream>>>(Qp, Kh, Vth, Ch, Cl);

    // Output projection
    wsplit_t<<<dim3(EMB / 32, VOUT / 32), dim3(32, 8), 0, stream>>>(Wo, Wht, Wlt, VOUT, EMB);
    gemm2<0><<<(EMB / 128) * (BB * LQ / 128), 256, 0, stream>>>(Ch, Cl, Wht, Wlt, bo, out, nullptr, BB * LQ, EMB, VOUT);
}

// Round 7
// 204.421 us; speedup vs baseline: 1.9905x; 1.9905x over previous
//
#include <hip/hip_runtime.h>

#define EMB  1024
#define VIN  512
#define VOUT 1024
#define NH   16
#define DH   64
#define BB   8
#define LQ   512
#define LK   1024

typedef __attribute__((ext_vector_type(8))) short bf16x8;
typedef __attribute__((ext_vector_type(4))) float f32x4;

typedef const __attribute__((address_space(1))) unsigned int* gptr_t;
typedef __attribute__((address_space(3))) unsigned int* lptr_t;

__device__ __forceinline__ unsigned short f2bf(float x) {
    unsigned int u = __float_as_uint(x);
    u += 0x7FFF + ((u >> 16) & 1);   // RN-even
    return (unsigned short)(u >> 16);
}
__device__ __forceinline__ float bf2f(unsigned short h) {
    return __uint_as_float(((unsigned int)h) << 16);
}

#define SWZ(row, cb) (((row) << 7) + ((cb) ^ (((row) & 7) << 4)))

// ---------------------------------------------------------------------------
// Elementwise fp32 -> bf16 hi/lo planes. 4M elems per input.
// ---------------------------------------------------------------------------
__global__ __launch_bounds__(256) void asplit(const float* __restrict__ in,
                                              unsigned short* __restrict__ ph,
                                              unsigned short* __restrict__ pl)
{
    const int i = blockIdx.x * 256 + threadIdx.x;
    float v[4];
    *reinterpret_cast<float4*>(v) = *reinterpret_cast<const float4*>(&in[(size_t)i * 4]);
    unsigned short h[4], l[4];
#pragma unroll
    for (int j = 0; j < 4; ++j) {
        h[j] = f2bf(v[j]);
        l[j] = f2bf(v[j] - bf2f(h[j]));
    }
    *reinterpret_cast<uint2*>(&ph[(size_t)i * 4]) = *reinterpret_cast<uint2*>(h);
    *reinterpret_cast<uint2*>(&pl[(size_t)i * 4]) = *reinterpret_cast<uint2*>(l);
}

// ---------------------------------------------------------------------------
// W [K,N] fp32 -> Wht, Wlt [N,K] bf16 hi/lo planes (transposed split).
// ---------------------------------------------------------------------------
__global__ __launch_bounds__(256) void wsplit_t(const float* __restrict__ W,
                                                unsigned short* __restrict__ Wht,
                                                unsigned short* __restrict__ Wlt,
                                                int K, int N)
{
    __shared__ float t[32][33];
    const int n0 = blockIdx.x * 32, k0 = blockIdx.y * 32;
    const int tx = threadIdx.x, ty = threadIdx.y;  // 32 x 8
#pragma unroll
    for (int r = 0; r < 32; r += 8)
        t[ty + r][tx] = W[(size_t)(k0 + ty + r) * N + n0 + tx];
    __syncthreads();
#pragma unroll
    for (int r = 0; r < 32; r += 8) {
        float x = t[tx][ty + r];
        unsigned short h = f2bf(x);
        unsigned short l = f2bf(x - bf2f(h));
        size_t o = (size_t)(n0 + ty + r) * K + k0 + tx;
        Wht[o] = h;
        Wlt[o] = l;
    }
}

// ---------------------------------------------------------------------------
// Stage one 128-row x 64-col bf16 plane tile (row stride Kstride elems) into
// linear LDS via global_load_lds; source pre-XOR-swizzled so SWZ reads are
// correct. One wave issues 16 x 16B-per-lane loads (8 rows each).
// ---------------------------------------------------------------------------
__device__ __forceinline__ void stageplane(const unsigned short* g0, int Kstride,
                                           unsigned short* l0, int lane)
{
#pragma unroll
    for (int r = 0; r < 16; ++r) {
        int row  = r * 8 + (lane >> 3);
        int colb = ((lane & 7) << 4) ^ ((row & 7) << 4);
        const unsigned short* src = g0 + (size_t)row * Kstride + (colb >> 1);
        __builtin_amdgcn_global_load_lds((gptr_t)src, (lptr_t)(l0 + r * 512), 16, 0, 0);
    }
}

// ---------------------------------------------------------------------------
// Split-bf16 MFMA GEMM, all operands pre-split bf16 planes, global_load_lds
// staged (no staging registers -> no spill). m97 2-barrier structure.
// EPI=0: fp32 C. EPI=1: bf16 hi plane natural. EPI=2: bf16 hi plane
// transposed per head. EPI=3: bf16 natural scaled by 0.125 (Q plane).
// ---------------------------------------------------------------------------
template<int EPI>
__global__ __launch_bounds__(256, 2) void gemm2(const unsigned short* __restrict__ Ah,
                                                const unsigned short* __restrict__ Al,
                                                const unsigned short* __restrict__ Bht,
                                                const unsigned short* __restrict__ Blt,
                                                const float* __restrict__ bias,
                                                float* __restrict__ C,
                                                unsigned short* __restrict__ Ch,
                                                int M, int N, int K)
{
    __shared__ unsigned short As_h[128 * 64], As_l[128 * 64];
    __shared__ unsigned short Bs_h[128 * 64], Bs_l[128 * 64];

    const int nbx = N >> 7;
    const int nwg = gridDim.x;
    const int qq  = nwg >> 3;
    const int id  = blockIdx.x;
    const int swz = (id & 7) * qq + (id >> 3);   // XCD-aware (nwg % 8 == 0)
    const int bx = swz % nbx, by = swz / nbx;
    const int m0 = by * 128, n0 = bx * 128;

    const int tid  = threadIdx.x;
    const int lane = tid & 63;
    const int w    = tid >> 6;
    const int wm = (w & 1) * 64;
    const int wn = (w >> 1) * 64;
    const int lr = lane & 15;
    const int lk = lane >> 4;

    f32x4 acc[4][4];
#pragma unroll
    for (int i = 0; i < 4; ++i)
#pragma unroll
        for (int j = 0; j < 4; ++j) acc[i][j] = (f32x4)(0.f);

    // wave w owns one plane's staging
    const unsigned short* mysrc =
        (w == 0) ? Ah + (size_t)m0 * K :
        (w == 1) ? Al + (size_t)m0 * K :
        (w == 2) ? Bht + (size_t)n0 * K :
                   Blt + (size_t)n0 * K;
    unsigned short* myplane =
        (w == 0) ? As_h : (w == 1) ? As_l : (w == 2) ? Bs_h : Bs_l;

    const int nt = K >> 6;
    for (int t = 0; t < nt; ++t) {
        stageplane(mysrc + ((size_t)t << 6), K, myplane, lane);
        __syncthreads();   // drains vmcnt -> tile resident

#pragma unroll
        for (int ks = 0; ks < 2; ++ks) {
            bf16x8 ah[4], al[4], bh[4], bl[4];
            const int cb = ks * 64 + lk * 16;
#pragma unroll
            for (int f = 0; f < 4; ++f) {
                int rowA = wm + f * 16 + lr;
                ah[f] = *reinterpret_cast<const bf16x8*>((char*)As_h + SWZ(rowA, cb));
                al[f] = *reinterpret_cast<const bf16x8*>((char*)As_l + SWZ(rowA, cb));
                int rowB = wn + f * 16 + lr;
                bh[f] = *reinterpret_cast<const bf16x8*>((char*)Bs_h + SWZ(rowB, cb));
                bl[f] = *reinterpret_cast<const bf16x8*>((char*)Bs_l + SWZ(rowB, cb));
            }
#pragma unroll
            for (int fm = 0; fm < 4; ++fm)
#pragma unroll
                for (int fn = 0; fn < 4; ++fn) {
                    acc[fm][fn] = __builtin_amdgcn_mfma_f32_16x16x32_bf16(ah[fm], bh[fn], acc[fm][fn], 0, 0, 0);
                    acc[fm][fn] = __builtin_amdgcn_mfma_f32_16x16x32_bf16(ah[fm], bl[fn], acc[fm][fn], 0, 0, 0);
                    acc[fm][fn] = __builtin_amdgcn_mfma_f32_16x16x32_bf16(al[fm], bh[fn], acc[fm][fn], 0, 0, 0);
                }
        }
        __syncthreads();   // all reads done before next stage overwrites LDS
    }

#pragma unroll
    for (int fn = 0; fn < 4; ++fn) {
        const int col = n0 + wn + fn * 16 + lr;
        const float bv = bias[col];
#pragma unroll
        for (int fm = 0; fm < 4; ++fm) {
            const int row0 = m0 + wm + fm * 16 + lk * 4;
            if constexpr (EPI == 0) {
#pragma unroll
                for (int r = 0; r < 4; ++r)
                    C[(size_t)(row0 + r) * N + col] = acc[fm][fn][r] + bv;
            } else if constexpr (EPI == 1) {
#pragma unroll
                for (int r = 0; r < 4; ++r)
                    Ch[(size_t)(row0 + r) * N + col] = f2bf(acc[fm][fn][r] + bv);
            } else if constexpr (EPI == 3) {
#pragma unroll
                for (int r = 0; r < 4; ++r)
                    Ch[(size_t)(row0 + r) * N + col] = f2bf((acc[fm][fn][r] + bv) * 0.125f);
            } else {
                unsigned short h4[4];
#pragma unroll
                for (int r = 0; r < 4; ++r)
                    h4[r] = f2bf(acc[fm][fn][r] + bv);
                size_t o = (((size_t)((row0 >> 10) * NH + (col >> 6)) * 64 + (col & 63)) << 10) + (row0 & 1023);
                *reinterpret_cast<uint2*>(&Ch[o]) = *reinterpret_cast<uint2*>(h4);
            }
        }
    }
}

// ---------------------------------------------------------------------------
// Stage 32 rows x 128B (row stride 1024 elems), pre-swizzled source.
// ---------------------------------------------------------------------------
__device__ __forceinline__ void stage32(const unsigned short* g0, unsigned short* l0, int lane)
{
#pragma unroll
    for (int r = 0; r < 4; ++r) {
        int row  = r * 8 + (lane >> 3);
        int colb = ((lane & 7) << 4) ^ ((row & 7) << 4);
        const unsigned short* src = g0 + ((size_t)row << 10) + (colb >> 1);
        __builtin_amdgcn_global_load_lds((gptr_t)src, (lptr_t)(l0 + r * 512), 16, 0, 0);
    }
}

// ---------------------------------------------------------------------------
// MFMA flash attention, plain bf16 inputs. Q plane pre-scaled by 0.125.
// K plane [8192,1024]; Vt plane [(b*NH+h)*64 + dv][key]. Writes ctx as
// split hi/lo bf16 planes [4096,1024]. XCD-grouped 1-D grid. 40KB LDS.
// ---------------------------------------------------------------------------
__global__ __launch_bounds__(256, 4) void attn_mfma(const unsigned short* __restrict__ Qh,
                                                    const unsigned short* __restrict__ Kh,
                                                    const unsigned short* __restrict__ Vth,
                                                    unsigned short* __restrict__ Ch,
                                                    unsigned short* __restrict__ Cl)
{
    const int id  = blockIdx.x;
    const int qt  = (id >> 3) & 7;
    const int grp = (id & 7) | ((id >> 6) << 3);   // 0..127, same-XCD groups
    const int h = grp & 15, b = grp >> 4;

    const int tid  = threadIdx.x;
    const int lane = tid & 63;
    const int w    = tid >> 6;
    const int lr   = lane & 15;
    const int lk   = lane >> 4;

    __shared__ unsigned short KVs[2][2][4096];   // [buf][K,Vt][64x64]
    __shared__ unsigned short Ps[4][1024];       // per-wave P [q16][key64]

    // Q fragments (already scaled bf16), rows w*16 + lr
    bf16x8 qb[2];
    {
        const unsigned short* qrow = &Qh[(size_t)(b * LQ + qt * 64 + w * 16 + lr) * EMB + h * DH];
        qb[0] = *reinterpret_cast<const bf16x8*>(qrow + lk * 8);
        qb[1] = *reinterpret_cast<const bf16x8*>(qrow + 32 + lk * 8);
    }

    const unsigned short* K0 = Kh + ((size_t)(b * LK) << 10) + h * DH;
    const unsigned short* V0 = Vth + ((size_t)(grp * 64) << 10);

    // prefetch tile 0: waves 0,1 -> K halves; waves 2,3 -> Vt halves
    {
        const int half = (w & 1) * 32;
        if (w < 2) stage32(K0 + ((size_t)half << 10), KVs[0][0] + half * 64, lane);
        else       stage32(V0 + ((size_t)half << 10), KVs[0][1] + half * 64, lane);
    }

    float m[4], lsum[4];
    f32x4 acc[4];
#pragma unroll
    for (int r = 0; r < 4; ++r) { m[r] = -1e30f; lsum[r] = 0.f; }
#pragma unroll
    for (int f = 0; f < 4; ++f) acc[f] = (f32x4)(0.f);

    for (int kt = 0; kt < LK / 64; ++kt) {
        const int cur = kt & 1;
        __syncthreads();   // vmcnt drained: tile kt resident; prev compute done

        if (kt + 1 < LK / 64) {
            const size_t koff = (size_t)(kt + 1) * 64;
            const int half = (w & 1) * 32;
            if (w < 2) stage32(K0 + ((koff + half) << 10), KVs[cur ^ 1][0] + half * 64, lane);
            else       stage32(V0 + ((size_t)half << 10) + koff, KVs[cur ^ 1][1] + half * 64, lane);
        }

        const char* Ks = (const char*)KVs[cur][0];
        const char* Vs = (const char*)KVs[cur][1];

        // QK^T
        f32x4 s[4];
#pragma unroll
        for (int fn = 0; fn < 4; ++fn) s[fn] = (f32x4)(0.f);
#pragma unroll
        for (int ks = 0; ks < 2; ++ks) {
            const int cb = ks * 64 + lk * 16;
#pragma unroll
            for (int fn = 0; fn < 4; ++fn) {
                bf16x8 kb = *reinterpret_cast<const bf16x8*>(Ks + SWZ(fn * 16 + lr, cb));
                s[fn] = __builtin_amdgcn_mfma_f32_16x16x32_bf16(qb[ks], kb, s[fn], 0, 0, 0);
            }
        }

        // online softmax (rows lk*4 + r)
#pragma unroll
        for (int r = 0; r < 4; ++r) {
            float mx = fmaxf(fmaxf(s[0][r], s[1][r]), fmaxf(s[2][r], s[3][r]));
            mx = fmaxf(mx, __shfl_xor(mx, 1));
            mx = fmaxf(mx, __shfl_xor(mx, 2));
            mx = fmaxf(mx, __shfl_xor(mx, 4));
            mx = fmaxf(mx, __shfl_xor(mx, 8));
            float mnew = fmaxf(m[r], mx);
            float corr = __expf(m[r] - mnew);
            m[r] = mnew;
            float rs = 0.f;
#pragma unroll
            for (int fn = 0; fn < 4; ++fn) {
                float p = __expf(s[fn][r] - mnew);
                s[fn][r] = p;
                rs += p;
            }
            rs += __shfl_xor(rs, 1);
            rs += __shfl_xor(rs, 2);
            rs += __shfl_xor(rs, 4);
            rs += __shfl_xor(rs, 8);
            lsum[r] = lsum[r] * corr + rs;
#pragma unroll
            for (int f = 0; f < 4; ++f) acc[f][r] *= corr;
        }

        // P (bf16) -> wave-private LDS [q][key]
#pragma unroll
        for (int fn = 0; fn < 4; ++fn)
#pragma unroll
            for (int r = 0; r < 4; ++r) {
                int q = lk * 4 + r, cb = 2 * (fn * 16 + lr);
                *reinterpret_cast<unsigned short*>((char*)Ps[w] + SWZ(q, cb)) = f2bf(s[fn][r]);
            }

        // PV
#pragma unroll
        for (int ks = 0; ks < 2; ++ks) {
            const int cb = ks * 64 + lk * 16;
            bf16x8 pa = *reinterpret_cast<const bf16x8*>((char*)Ps[w] + SWZ(lr, cb));
#pragma unroll
            for (int f = 0; f < 4; ++f) {
                bf16x8 vb = *reinterpret_cast<const bf16x8*>(Vs + SWZ(f * 16 + lr, cb));
                acc[f] = __builtin_amdgcn_mfma_f32_16x16x32_bf16(pa, vb, acc[f], 0, 0, 0);
            }
        }
    }

    // epilogue: normalize, split, write ctx hi/lo planes
#pragma unroll
    for (int r = 0; r < 4; ++r) {
        float inv = 1.f / lsum[r];
        const size_t row = (size_t)(b * LQ + qt * 64 + w * 16 + lk * 4 + r);
#pragma unroll
        for (int f = 0; f < 4; ++f) {
            float x = acc[f][r] * inv;
            unsigned short hh = f2bf(x);
            size_t o = (row << 10) + h * DH + f * 16 + lr;
            Ch[o] = hh;
            Cl[o] = f2bf(x - bf2f(hh));
        }
    }
}

extern "C" void kernel_launch(void* const* d_in, const int* in_sizes, int n_in,
                              void* d_out, int out_size, void* d_ws, size_t ws_size,
                              hipStream_t stream)
{
    const float* query = (const float*)d_in[0];
    const float* key   = (const float*)d_in[1];
    const float* value = (const float*)d_in[2];
    const float* Wq = (const float*)d_in[3];
    const float* bq = (const float*)d_in[4];
    const float* Wk = (const float*)d_in[5];
    const float* bk = (const float*)d_in[6];
    const float* Wv = (const float*)d_in[7];
    const float* bv = (const float*)d_in[8];
    const float* Wo = (const float*)d_in[9];
    const float* bo = (const float*)d_in[10];
    float* out = (float*)d_out;

    // ws (76MB): Qh8 | Kh16 | Vth16 | Ah8 | Al8 | Ch8 | Cl8 | Wht2 | Wlt2
    unsigned short* Qh  = (unsigned short*)d_ws;
    unsigned short* Kh  = Qh  + (size_t)4194304;
    unsigned short* Vth = Kh  + (size_t)BB * LK * EMB;
    unsigned short* Ah  = Vth + (size_t)BB * LK * VOUT;
    unsigned short* Al  = Ah  + (size_t)4194304;
    unsigned short* Ch  = Al  + (size_t)4194304;
    unsigned short* Cl  = Ch  + (size_t)4194304;
    unsigned short* Wht = Cl  + (size_t)4194304;
    unsigned short* Wlt = Wht + (size_t)EMB * EMB;

    // Q projection -> pre-scaled bf16 Q plane
    asplit<<<4096, 256, 0, stream>>>(query, Ah, Al);
    wsplit_t<<<dim3(EMB / 32, EMB / 32), dim3(32, 8), 0, stream>>>(Wq, Wht, Wlt, EMB, EMB);
    gemm2<3><<<(EMB / 128) * (BB * LQ / 128), 256, 0, stream>>>(Ah, Al, Wht, Wlt, bq, nullptr, Qh, BB * LQ, EMB, EMB);

    // K projection -> bf16 plane
    asplit<<<4096, 256, 0, stream>>>(key, Ah, Al);
    wsplit_t<<<dim3(EMB / 32, VIN / 32), dim3(32, 8), 0, stream>>>(Wk, Wht, Wlt, VIN, EMB);
    gemm2<1><<<(EMB / 128) * (BB * LK / 128), 256, 0, stream>>>(Ah, Al, Wht, Wlt, bk, nullptr, Kh, BB * LK, EMB, VIN);

    // V projection -> transposed bf16 plane
    asplit<<<4096, 256, 0, stream>>>(value, Ah, Al);
    wsplit_t<<<dim3(VOUT / 32, VIN / 32), dim3(32, 8), 0, stream>>>(Wv, Wht, Wlt, VIN, VOUT);
    gemm2<2><<<(VOUT / 128) * (BB * LK / 128), 256, 0, stream>>>(Ah, Al, Wht, Wlt, bv, nullptr, Vth, BB * LK, VOUT, VIN);

    // Attention -> ctx split planes
    attn_mfma<<<LQ / 64 * NH * BB, 256, 0, stream>>>(Qh, Kh, Vth, Ch, Cl);

    // Output projection
    wsplit_t<<<dim3(EMB / 32, VOUT / 32), dim3(32, 8), 0, stream>>>(Wo, Wht, Wlt, VOUT, EMB);
    gemm2<0><<<(EMB / 128) * (BB * LQ / 128), 256, 0, stream>>>(Ch, Cl, Wht, Wlt, bo, out, nullptr, BB * LQ, EMB, VOUT);
}

// Round 8
// 171.020 us; speedup vs baseline: 2.3792x; 1.1953x over previous
//
#include <hip/hip_runtime.h>

#define EMB  1024
#define VIN  512
#define VOUT 1024
#define NH   16
#define DH   64
#define BB   8
#define LQ   512
#define LK   1024

typedef __attribute__((ext_vector_type(8))) short bf16x8;
typedef __attribute__((ext_vector_type(4))) float f32x4;

typedef const __attribute__((address_space(1))) unsigned int* gptr_t;
typedef __attribute__((address_space(3))) unsigned int* lptr_t;

__device__ __forceinline__ unsigned short f2bf(float x) {
    unsigned int u = __float_as_uint(x);
    u += 0x7FFF + ((u >> 16) & 1);   // RN-even
    return (unsigned short)(u >> 16);
}
__device__ __forceinline__ float bf2f(unsigned short h) {
    return __uint_as_float(((unsigned int)h) << 16);
}

#define SWZ(row, cb) (((row) << 7) + ((cb) ^ (((row) & 7) << 4)))

// ---------------------------------------------------------------------------
// Elementwise fp32 -> bf16 hi plane only (for plain-bf16 projections).
// ---------------------------------------------------------------------------
__global__ __launch_bounds__(256) void asplit_h(const float* __restrict__ in,
                                                unsigned short* __restrict__ ph)
{
    const int i = blockIdx.x * 256 + threadIdx.x;
    float v[4];
    *reinterpret_cast<float4*>(v) = *reinterpret_cast<const float4*>(&in[(size_t)i * 4]);
    unsigned short h[4];
#pragma unroll
    for (int j = 0; j < 4; ++j) h[j] = f2bf(v[j]);
    *reinterpret_cast<uint2*>(&ph[(size_t)i * 4]) = *reinterpret_cast<uint2*>(h);
}

// ---------------------------------------------------------------------------
// W [K,N] fp32 -> Wht [N,K] bf16 hi plane (transposed, no lo).
// ---------------------------------------------------------------------------
__global__ __launch_bounds__(256) void wsplit_h(const float* __restrict__ W,
                                                unsigned short* __restrict__ Wht,
                                                int K, int N)
{
    __shared__ float t[32][33];
    const int n0 = blockIdx.x * 32, k0 = blockIdx.y * 32;
    const int tx = threadIdx.x, ty = threadIdx.y;  // 32 x 8
#pragma unroll
    for (int r = 0; r < 32; r += 8)
        t[ty + r][tx] = W[(size_t)(k0 + ty + r) * N + n0 + tx];
    __syncthreads();
#pragma unroll
    for (int r = 0; r < 32; r += 8)
        Wht[(size_t)(n0 + ty + r) * K + k0 + tx] = f2bf(t[tx][ty + r]);
}

// ---------------------------------------------------------------------------
// W [K,N] fp32 -> Wht, Wlt [N,K] bf16 hi/lo planes (O-projection only).
// ---------------------------------------------------------------------------
__global__ __launch_bounds__(256) void wsplit_t(const float* __restrict__ W,
                                                unsigned short* __restrict__ Wht,
                                                unsigned short* __restrict__ Wlt,
                                                int K, int N)
{
    __shared__ float t[32][33];
    const int n0 = blockIdx.x * 32, k0 = blockIdx.y * 32;
    const int tx = threadIdx.x, ty = threadIdx.y;
#pragma unroll
    for (int r = 0; r < 32; r += 8)
        t[ty + r][tx] = W[(size_t)(k0 + ty + r) * N + n0 + tx];
    __syncthreads();
#pragma unroll
    for (int r = 0; r < 32; r += 8) {
        float x = t[tx][ty + r];
        unsigned short h = f2bf(x);
        unsigned short l = f2bf(x - bf2f(h));
        size_t o = (size_t)(n0 + ty + r) * K + k0 + tx;
        Wht[o] = h;
        Wlt[o] = l;
    }
}

// ---------------------------------------------------------------------------
// Stage 64 rows x 64 cols of a bf16 plane (row stride Kstride elems) into
// linear LDS via global_load_lds, source pre-XOR-swizzled (rule #21).
// One wave, 8 x 16B per lane.
// ---------------------------------------------------------------------------
__device__ __forceinline__ void stagehalf(const unsigned short* g0, int Kstride,
                                          unsigned short* l0, int lane)
{
#pragma unroll
    for (int r = 0; r < 8; ++r) {
        int row  = r * 8 + (lane >> 3);
        int colb = ((lane & 7) << 4) ^ ((row & 7) << 4);
        const unsigned short* src = g0 + (size_t)row * Kstride + (colb >> 1);
        __builtin_amdgcn_global_load_lds((gptr_t)src, (lptr_t)(l0 + r * 512), 16, 0, 0);
    }
}

// ---------------------------------------------------------------------------
// Plain-bf16 MFMA GEMM (1 product): C = Ah @ Wht^T + bias, bf16 out.
// EPI=1: natural. EPI=2: transposed per head. EPI=3: natural scaled 0.125.
// 32KB LDS; waves 0/1 stage A halves, 2/3 stage B halves.
// ---------------------------------------------------------------------------
template<int EPI>
__global__ __launch_bounds__(256, 2) void gemm1(const unsigned short* __restrict__ Ah,
                                                const unsigned short* __restrict__ Bht,
                                                const float* __restrict__ bias,
                                                unsigned short* __restrict__ Ch,
                                                int M, int N, int K)
{
    __shared__ unsigned short As[128 * 64], Bs[128 * 64];

    const int nbx = N >> 7;
    const int nwg = gridDim.x;
    const int qq  = nwg >> 3;
    const int id  = blockIdx.x;
    const int swz = (id & 7) * qq + (id >> 3);
    const int bx = swz % nbx, by = swz / nbx;
    const int m0 = by * 128, n0 = bx * 128;

    const int tid  = threadIdx.x;
    const int lane = tid & 63;
    const int w    = tid >> 6;
    const int wm = (w & 1) * 64;
    const int wn = (w >> 1) * 64;
    const int lr = lane & 15;
    const int lk = lane >> 4;

    f32x4 acc[4][4];
#pragma unroll
    for (int i = 0; i < 4; ++i)
#pragma unroll
        for (int j = 0; j < 4; ++j) acc[i][j] = (f32x4)(0.f);

    const unsigned short* mysrc = (w < 2)
        ? Ah  + (size_t)(m0 + (w & 1) * 64) * K
        : Bht + (size_t)(n0 + (w & 1) * 64) * K;
    unsigned short* myplane = ((w < 2) ? As : Bs) + (w & 1) * 64 * 64;

    const int nt = K >> 6;
    for (int t = 0; t < nt; ++t) {
        stagehalf(mysrc + ((size_t)t << 6), K, myplane, lane);
        __syncthreads();

#pragma unroll
        for (int ks = 0; ks < 2; ++ks) {
            bf16x8 ah[4], bh[4];
            const int cb = ks * 64 + lk * 16;
#pragma unroll
            for (int f = 0; f < 4; ++f) {
                ah[f] = *reinterpret_cast<const bf16x8*>((char*)As + SWZ(wm + f * 16 + lr, cb));
                bh[f] = *reinterpret_cast<const bf16x8*>((char*)Bs + SWZ(wn + f * 16 + lr, cb));
            }
#pragma unroll
            for (int fm = 0; fm < 4; ++fm)
#pragma unroll
                for (int fn = 0; fn < 4; ++fn)
                    acc[fm][fn] = __builtin_amdgcn_mfma_f32_16x16x32_bf16(ah[fm], bh[fn], acc[fm][fn], 0, 0, 0);
        }
        __syncthreads();
    }

#pragma unroll
    for (int fn = 0; fn < 4; ++fn) {
        const int col = n0 + wn + fn * 16 + lr;
        const float bv = bias[col];
#pragma unroll
        for (int fm = 0; fm < 4; ++fm) {
            const int row0 = m0 + wm + fm * 16 + lk * 4;
            if constexpr (EPI == 1) {
#pragma unroll
                for (int r = 0; r < 4; ++r)
                    Ch[(size_t)(row0 + r) * N + col] = f2bf(acc[fm][fn][r] + bv);
            } else if constexpr (EPI == 3) {
#pragma unroll
                for (int r = 0; r < 4; ++r)
                    Ch[(size_t)(row0 + r) * N + col] = f2bf((acc[fm][fn][r] + bv) * 0.125f);
            } else {
                unsigned short h4[4];
#pragma unroll
                for (int r = 0; r < 4; ++r)
                    h4[r] = f2bf(acc[fm][fn][r] + bv);
                size_t o = (((size_t)((row0 >> 10) * NH + (col >> 6)) * 64 + (col & 63)) << 10) + (row0 & 1023);
                *reinterpret_cast<uint2*>(&Ch[o]) = *reinterpret_cast<uint2*>(h4);
            }
        }
    }
}

// ---------------------------------------------------------------------------
// Stage one 128-row x 64-col plane tile via global_load_lds (gemm2).
// ---------------------------------------------------------------------------
__device__ __forceinline__ void stageplane(const unsigned short* g0, int Kstride,
                                           unsigned short* l0, int lane)
{
#pragma unroll
    for (int r = 0; r < 16; ++r) {
        int row  = r * 8 + (lane >> 3);
        int colb = ((lane & 7) << 4) ^ ((row & 7) << 4);
        const unsigned short* src = g0 + (size_t)row * Kstride + (colb >> 1);
        __builtin_amdgcn_global_load_lds((gptr_t)src, (lptr_t)(l0 + r * 512), 16, 0, 0);
    }
}

// ---------------------------------------------------------------------------
// Split-bf16 MFMA GEMM (3 products) — O-projection. fp32 out.
// ---------------------------------------------------------------------------
__global__ __launch_bounds__(256, 2) void gemm2(const unsigned short* __restrict__ Ah,
                                                const unsigned short* __restrict__ Al,
                                                const unsigned short* __restrict__ Bht,
                                                const unsigned short* __restrict__ Blt,
                                                const float* __restrict__ bias,
                                                float* __restrict__ C,
                                                int M, int N, int K)
{
    __shared__ unsigned short As_h[128 * 64], As_l[128 * 64];
    __shared__ unsigned short Bs_h[128 * 64], Bs_l[128 * 64];

    const int nbx = N >> 7;
    const int nwg = gridDim.x;
    const int qq  = nwg >> 3;
    const int id  = blockIdx.x;
    const int swz = (id & 7) * qq + (id >> 3);
    const int bx = swz % nbx, by = swz / nbx;
    const int m0 = by * 128, n0 = bx * 128;

    const int tid  = threadIdx.x;
    const int lane = tid & 63;
    const int w    = tid >> 6;
    const int wm = (w & 1) * 64;
    const int wn = (w >> 1) * 64;
    const int lr = lane & 15;
    const int lk = lane >> 4;

    f32x4 acc[4][4];
#pragma unroll
    for (int i = 0; i < 4; ++i)
#pragma unroll
        for (int j = 0; j < 4; ++j) acc[i][j] = (f32x4)(0.f);

    const unsigned short* mysrc =
        (w == 0) ? Ah + (size_t)m0 * K :
        (w == 1) ? Al + (size_t)m0 * K :
        (w == 2) ? Bht + (size_t)n0 * K :
                   Blt + (size_t)n0 * K;
    unsigned short* myplane =
        (w == 0) ? As_h : (w == 1) ? As_l : (w == 2) ? Bs_h : Bs_l;

    const int nt = K >> 6;
    for (int t = 0; t < nt; ++t) {
        stageplane(mysrc + ((size_t)t << 6), K, myplane, lane);
        __syncthreads();

#pragma unroll
        for (int ks = 0; ks < 2; ++ks) {
            bf16x8 ah[4], al[4], bh[4], bl[4];
            const int cb = ks * 64 + lk * 16;
#pragma unroll
            for (int f = 0; f < 4; ++f) {
                int rowA = wm + f * 16 + lr;
                ah[f] = *reinterpret_cast<const bf16x8*>((char*)As_h + SWZ(rowA, cb));
                al[f] = *reinterpret_cast<const bf16x8*>((char*)As_l + SWZ(rowA, cb));
                int rowB = wn + f * 16 + lr;
                bh[f] = *reinterpret_cast<const bf16x8*>((char*)Bs_h + SWZ(rowB, cb));
                bl[f] = *reinterpret_cast<const bf16x8*>((char*)Bs_l + SWZ(rowB, cb));
            }
#pragma unroll
            for (int fm = 0; fm < 4; ++fm)
#pragma unroll
                for (int fn = 0; fn < 4; ++fn) {
                    acc[fm][fn] = __builtin_amdgcn_mfma_f32_16x16x32_bf16(ah[fm], bh[fn], acc[fm][fn], 0, 0, 0);
                    acc[fm][fn] = __builtin_amdgcn_mfma_f32_16x16x32_bf16(ah[fm], bl[fn], acc[fm][fn], 0, 0, 0);
                    acc[fm][fn] = __builtin_amdgcn_mfma_f32_16x16x32_bf16(al[fm], bh[fn], acc[fm][fn], 0, 0, 0);
                }
        }
        __syncthreads();
    }

#pragma unroll
    for (int fn = 0; fn < 4; ++fn) {
        const int col = n0 + wn + fn * 16 + lr;
        const float bv = bias[col];
#pragma unroll
        for (int fm = 0; fm < 4; ++fm) {
            const int row0 = m0 + wm + fm * 16 + lk * 4;
#pragma unroll
            for (int r = 0; r < 4; ++r)
                C[(size_t)(row0 + r) * N + col] = acc[fm][fn][r] + bv;
        }
    }
}

// ---------------------------------------------------------------------------
// Stage 32 rows x 128B (row stride 1024 elems), pre-swizzled source.
// ---------------------------------------------------------------------------
__device__ __forceinline__ void stage32(const unsigned short* g0, unsigned short* l0, int lane)
{
#pragma unroll
    for (int r = 0; r < 4; ++r) {
        int row  = r * 8 + (lane >> 3);
        int colb = ((lane & 7) << 4) ^ ((row & 7) << 4);
        const unsigned short* src = g0 + ((size_t)row << 10) + (colb >> 1);
        __builtin_amdgcn_global_load_lds((gptr_t)src, (lptr_t)(l0 + r * 512), 16, 0, 0);
    }
}

// ---------------------------------------------------------------------------
// MFMA flash attention, plain bf16 inputs, Q pre-scaled. Unchanged from R7.
// ---------------------------------------------------------------------------
__global__ __launch_bounds__(256, 4) void attn_mfma(const unsigned short* __restrict__ Qh,
                                                    const unsigned short* __restrict__ Kh,
                                                    const unsigned short* __restrict__ Vth,
                                                    unsigned short* __restrict__ Ch,
                                                    unsigned short* __restrict__ Cl)
{
    const int id  = blockIdx.x;
    const int qt  = (id >> 3) & 7;
    const int grp = (id & 7) | ((id >> 6) << 3);
    const int h = grp & 15, b = grp >> 4;

    const int tid  = threadIdx.x;
    const int lane = tid & 63;
    const int w    = tid >> 6;
    const int lr   = lane & 15;
    const int lk   = lane >> 4;

    __shared__ unsigned short KVs[2][2][4096];
    __shared__ unsigned short Ps[4][1024];

    bf16x8 qb[2];
    {
        const unsigned short* qrow = &Qh[(size_t)(b * LQ + qt * 64 + w * 16 + lr) * EMB + h * DH];
        qb[0] = *reinterpret_cast<const bf16x8*>(qrow + lk * 8);
        qb[1] = *reinterpret_cast<const bf16x8*>(qrow + 32 + lk * 8);
    }

    const unsigned short* K0 = Kh + ((size_t)(b * LK) << 10) + h * DH;
    const unsigned short* V0 = Vth + ((size_t)(grp * 64) << 10);

    {
        const int half = (w & 1) * 32;
        if (w < 2) stage32(K0 + ((size_t)half << 10), KVs[0][0] + half * 64, lane);
        else       stage32(V0 + ((size_t)half << 10), KVs[0][1] + half * 64, lane);
    }

    float m[4], lsum[4];
    f32x4 acc[4];
#pragma unroll
    for (int r = 0; r < 4; ++r) { m[r] = -1e30f; lsum[r] = 0.f; }
#pragma unroll
    for (int f = 0; f < 4; ++f) acc[f] = (f32x4)(0.f);

    for (int kt = 0; kt < LK / 64; ++kt) {
        const int cur = kt & 1;
        __syncthreads();

        if (kt + 1 < LK / 64) {
            const size_t koff = (size_t)(kt + 1) * 64;
            const int half = (w & 1) * 32;
            if (w < 2) stage32(K0 + ((koff + half) << 10), KVs[cur ^ 1][0] + half * 64, lane);
            else       stage32(V0 + ((size_t)half << 10) + koff, KVs[cur ^ 1][1] + half * 64, lane);
        }

        const char* Ks = (const char*)KVs[cur][0];
        const char* Vs = (const char*)KVs[cur][1];

        f32x4 s[4];
#pragma unroll
        for (int fn = 0; fn < 4; ++fn) s[fn] = (f32x4)(0.f);
#pragma unroll
        for (int ks = 0; ks < 2; ++ks) {
            const int cb = ks * 64 + lk * 16;
#pragma unroll
            for (int fn = 0; fn < 4; ++fn) {
                bf16x8 kb = *reinterpret_cast<const bf16x8*>(Ks + SWZ(fn * 16 + lr, cb));
                s[fn] = __builtin_amdgcn_mfma_f32_16x16x32_bf16(qb[ks], kb, s[fn], 0, 0, 0);
            }
        }

#pragma unroll
        for (int r = 0; r < 4; ++r) {
            float mx = fmaxf(fmaxf(s[0][r], s[1][r]), fmaxf(s[2][r], s[3][r]));
            mx = fmaxf(mx, __shfl_xor(mx, 1));
            mx = fmaxf(mx, __shfl_xor(mx, 2));
            mx = fmaxf(mx, __shfl_xor(mx, 4));
            mx = fmaxf(mx, __shfl_xor(mx, 8));
            float mnew = fmaxf(m[r], mx);
            float corr = __expf(m[r] - mnew);
            m[r] = mnew;
            float rs = 0.f;
#pragma unroll
            for (int fn = 0; fn < 4; ++fn) {
                float p = __expf(s[fn][r] - mnew);
                s[fn][r] = p;
                rs += p;
            }
            rs += __shfl_xor(rs, 1);
            rs += __shfl_xor(rs, 2);
            rs += __shfl_xor(rs, 4);
            rs += __shfl_xor(rs, 8);
            lsum[r] = lsum[r] * corr + rs;
#pragma unroll
            for (int f = 0; f < 4; ++f) acc[f][r] *= corr;
        }

#pragma unroll
        for (int fn = 0; fn < 4; ++fn)
#pragma unroll
            for (int r = 0; r < 4; ++r) {
                int q = lk * 4 + r, cb = 2 * (fn * 16 + lr);
                *reinterpret_cast<unsigned short*>((char*)Ps[w] + SWZ(q, cb)) = f2bf(s[fn][r]);
            }

#pragma unroll
        for (int ks = 0; ks < 2; ++ks) {
            const int cb = ks * 64 + lk * 16;
            bf16x8 pa = *reinterpret_cast<const bf16x8*>((char*)Ps[w] + SWZ(lr, cb));
#pragma unroll
            for (int f = 0; f < 4; ++f) {
                bf16x8 vb = *reinterpret_cast<const bf16x8*>(Vs + SWZ(f * 16 + lr, cb));
                acc[f] = __builtin_amdgcn_mfma_f32_16x16x32_bf16(pa, vb, acc[f], 0, 0, 0);
            }
        }
    }

#pragma unroll
    for (int r = 0; r < 4; ++r) {
        float inv = 1.f / lsum[r];
        const size_t row = (size_t)(b * LQ + qt * 64 + w * 16 + lk * 4 + r);
#pragma unroll
        for (int f = 0; f < 4; ++f) {
            float x = acc[f][r] * inv;
            unsigned short hh = f2bf(x);
            size_t o = (row << 10) + h * DH + f * 16 + lr;
            Ch[o] = hh;
            Cl[o] = f2bf(x - bf2f(hh));
        }
    }
}

extern "C" void kernel_launch(void* const* d_in, const int* in_sizes, int n_in,
                              void* d_out, int out_size, void* d_ws, size_t ws_size,
                              hipStream_t stream)
{
    const float* query = (const float*)d_in[0];
    const float* key   = (const float*)d_in[1];
    const float* value = (const float*)d_in[2];
    const float* Wq = (const float*)d_in[3];
    const float* bq = (const float*)d_in[4];
    const float* Wk = (const float*)d_in[5];
    const float* bk = (const float*)d_in[6];
    const float* Wv = (const float*)d_in[7];
    const float* bv = (const float*)d_in[8];
    const float* Wo = (const float*)d_in[9];
    const float* bo = (const float*)d_in[10];
    float* out = (float*)d_out;

    // ws (68MB): Qh8 | Kh16 | Vth16 | Ah8 | Ch8 | Cl8 | Wht2 | Wlt2
    unsigned short* Qh  = (unsigned short*)d_ws;
    unsigned short* Kh  = Qh  + (size_t)4194304;
    unsigned short* Vth = Kh  + (size_t)BB * LK * EMB;
    unsigned short* Ah  = Vth + (size_t)BB * LK * VOUT;
    unsigned short* Ch  = Ah  + (size_t)4194304;
    unsigned short* Cl  = Ch  + (size_t)4194304;
    unsigned short* Wht = Cl  + (size_t)4194304;
    unsigned short* Wlt = Wht + (size_t)EMB * EMB;

    // Q projection -> pre-scaled bf16 Q plane (plain bf16 GEMM)
    asplit_h<<<4096, 256, 0, stream>>>(query, Ah);
    wsplit_h<<<dim3(EMB / 32, EMB / 32), dim3(32, 8), 0, stream>>>(Wq, Wht, EMB, EMB);
    gemm1<3><<<(EMB / 128) * (BB * LQ / 128), 256, 0, stream>>>(Ah, Wht, bq, Qh, BB * LQ, EMB, EMB);

    // K projection -> bf16 plane (plain bf16 GEMM)
    asplit_h<<<4096, 256, 0, stream>>>(key, Ah);
    wsplit_h<<<dim3(EMB / 32, VIN / 32), dim3(32, 8), 0, stream>>>(Wk, Wht, VIN, EMB);
    gemm1<1><<<(EMB / 128) * (BB * LK / 128), 256, 0, stream>>>(Ah, Wht, bk, Kh, BB * LK, EMB, VIN);

    // V projection -> transposed bf16 plane (plain bf16 GEMM)
    asplit_h<<<4096, 256, 0, stream>>>(value, Ah);
    wsplit_h<<<dim3(VOUT / 32, VIN / 32), dim3(32, 8), 0, stream>>>(Wv, Wht, VIN, VOUT);
    gemm1<2><<<(VOUT / 128) * (BB * LK / 128), 256, 0, stream>>>(Ah, Wht, bv, Vth, BB * LK, VOUT, VIN);

    // Attention -> ctx split planes
    attn_mfma<<<LQ / 64 * NH * BB, 256, 0, stream>>>(Qh, Kh, Vth, Ch, Cl);

    // Output projection (3-product split, fp32-grade)
    wsplit_t<<<dim3(EMB / 32, VOUT / 32), dim3(32, 8), 0, stream>>>(Wo, Wht, Wlt, VOUT, EMB);
    gemm2<<<(EMB / 128) * (BB * LQ / 128), 256, 0, stream>>>(Ch, Cl, Wht, Wlt, bo, out, BB * LQ, EMB, VOUT);
}

// Round 10
// 147.387 us; speedup vs baseline: 2.7607x; 1.1603x over previous
//
#include <hip/hip_runtime.h>

#define EMB  1024
#define VIN  512
#define VOUT 1024
#define NH   16
#define DH   64
#define BB   8
#define LQ   512
#define LK   1024

typedef __attribute__((ext_vector_type(8))) short bf16x8;
typedef __attribute__((ext_vector_type(4))) float f32x4;

typedef const __attribute__((address_space(1))) unsigned int* gptr_t;
typedef __attribute__((address_space(3))) unsigned int* lptr_t;

__device__ __forceinline__ unsigned short f2bf(float x) {
    unsigned int u = __float_as_uint(x);
    u += 0x7FFF + ((u >> 16) & 1);   // RN-even
    return (unsigned short)(u >> 16);
}
__device__ __forceinline__ float bf2f(unsigned short h) {
    return __uint_as_float(((unsigned int)h) << 16);
}
__device__ __forceinline__ float fexp2(float x) {
    return __builtin_amdgcn_exp2f(x);   // v_exp_f32 (base-2 native)
}

#define SWZ(row, cb) (((row) << 7) + ((cb) ^ (((row) & 7) << 4)))

// ---------------------------------------------------------------------------
// Merged elementwise fp32 -> bf16 hi plane for query/key/value (3x 4.19M).
// ---------------------------------------------------------------------------
__global__ __launch_bounds__(256) void asplit3(const float* __restrict__ q,
                                               const float* __restrict__ k,
                                               const float* __restrict__ v,
                                               unsigned short* __restrict__ Aq,
                                               unsigned short* __restrict__ Ak,
                                               unsigned short* __restrict__ Av)
{
    const int which = blockIdx.x >> 12;            // 4096 blocks per input
    const float* in = (which == 0) ? q : (which == 1) ? k : v;
    unsigned short* out = (which == 0) ? Aq : (which == 1) ? Ak : Av;
    const int i = (blockIdx.x & 4095) * 256 + threadIdx.x;
    float val[4];
    *reinterpret_cast<float4*>(val) = *reinterpret_cast<const float4*>(&in[(size_t)i * 4]);
    unsigned short h[4];
#pragma unroll
    for (int j = 0; j < 4; ++j) h[j] = f2bf(val[j]);
    *reinterpret_cast<uint2*>(&out[(size_t)i * 4]) = *reinterpret_cast<uint2*>(h);
}

// ---------------------------------------------------------------------------
// Merged weight transpose-split: Wq,Wk,Wv -> hi planes; Wo -> hi+lo planes.
// ---------------------------------------------------------------------------
__device__ __forceinline__ void wtile(const float* W, unsigned short* Wht,
                                      unsigned short* Wlt, int K, int N,
                                      int bx, int by, int tx, int ty)
{
    __shared__ float t[32][33];
    const int n0 = bx * 32, k0 = by * 32;
#pragma unroll
    for (int r = 0; r < 32; r += 8)
        t[ty + r][tx] = W[(size_t)(k0 + ty + r) * N + n0 + tx];
    __syncthreads();
#pragma unroll
    for (int r = 0; r < 32; r += 8) {
        float x = t[tx][ty + r];
        unsigned short h = f2bf(x);
        size_t o = (size_t)(n0 + ty + r) * K + k0 + tx;
        Wht[o] = h;
        if (Wlt) Wlt[o] = f2bf(x - bf2f(h));
    }
}

__global__ __launch_bounds__(256) void wsplit_all(const float* __restrict__ Wq,
                                                  const float* __restrict__ Wk,
                                                  const float* __restrict__ Wv,
                                                  const float* __restrict__ Wo,
                                                  unsigned short* __restrict__ Wqt,
                                                  unsigned short* __restrict__ Wkt,
                                                  unsigned short* __restrict__ Wvt,
                                                  unsigned short* __restrict__ Woh,
                                                  unsigned short* __restrict__ Wol)
{
    const int id = blockIdx.x;
    const int tx = threadIdx.x, ty = threadIdx.y;
    if (id < 1024)       wtile(Wq, Wqt, nullptr, 1024, 1024, id & 31, id >> 5, tx, ty);
    else if (id < 1536)  wtile(Wk, Wkt, nullptr, 512, 1024, (id - 1024) & 31, (id - 1024) >> 5, tx, ty);
    else if (id < 2048)  wtile(Wv, Wvt, nullptr, 512, 1024, (id - 1536) & 31, (id - 1536) >> 5, tx, ty);
    else                 wtile(Wo, Woh, Wol, 1024, 1024, (id - 2048) & 31, (id - 2048) >> 5, tx, ty);
}

// ---------------------------------------------------------------------------
// Stage 64 rows x 64 cols of a bf16 plane into linear LDS (pre-swizzled src).
// ---------------------------------------------------------------------------
__device__ __forceinline__ void stagehalf(const unsigned short* g0, int Kstride,
                                          unsigned short* l0, int lane)
{
#pragma unroll
    for (int r = 0; r < 8; ++r) {
        int row  = r * 8 + (lane >> 3);
        int colb = ((lane & 7) << 4) ^ ((row & 7) << 4);
        const unsigned short* src = g0 + (size_t)row * Kstride + (colb >> 1);
        __builtin_amdgcn_global_load_lds((gptr_t)src, (lptr_t)(l0 + r * 512), 16, 0, 0);
    }
}

// ---------------------------------------------------------------------------
// Plain-bf16 MFMA GEMM (1 product). EPI=1 natural, EPI=2 per-head transposed,
// EPI=3 natural scaled by 0.125*log2(e) (Q plane, exp2-domain softmax).
// ---------------------------------------------------------------------------
template<int EPI>
__global__ __launch_bounds__(256, 2) void gemm1(const unsigned short* __restrict__ Ah,
                                                const unsigned short* __restrict__ Bht,
                                                const float* __restrict__ bias,
                                                unsigned short* __restrict__ Ch,
                                                int M, int N, int K)
{
    __shared__ unsigned short As[128 * 64], Bs[128 * 64];

    const int nbx = N >> 7;
    const int nwg = gridDim.x;
    const int qq  = nwg >> 3;
    const int id  = blockIdx.x;
    const int swz = (id & 7) * qq + (id >> 3);
    const int bx = swz % nbx, by = swz / nbx;
    const int m0 = by * 128, n0 = bx * 128;

    const int tid  = threadIdx.x;
    const int lane = tid & 63;
    const int w    = tid >> 6;
    const int wm = (w & 1) * 64;
    const int wn = (w >> 1) * 64;
    const int lr = lane & 15;
    const int lk = lane >> 4;

    f32x4 acc[4][4];
#pragma unroll
    for (int i = 0; i < 4; ++i)
#pragma unroll
        for (int j = 0; j < 4; ++j) acc[i][j] = (f32x4)(0.f);

    const unsigned short* mysrc = (w < 2)
        ? Ah  + (size_t)(m0 + (w & 1) * 64) * K
        : Bht + (size_t)(n0 + (w & 1) * 64) * K;
    unsigned short* myplane = ((w < 2) ? As : Bs) + (w & 1) * 64 * 64;

    const int nt = K >> 6;
    for (int t = 0; t < nt; ++t) {
        stagehalf(mysrc + ((size_t)t << 6), K, myplane, lane);
        __syncthreads();

#pragma unroll
        for (int ks = 0; ks < 2; ++ks) {
            bf16x8 ah[4], bh[4];
            const int cb = ks * 64 + lk * 16;
#pragma unroll
            for (int f = 0; f < 4; ++f) {
                ah[f] = *reinterpret_cast<const bf16x8*>((char*)As + SWZ(wm + f * 16 + lr, cb));
                bh[f] = *reinterpret_cast<const bf16x8*>((char*)Bs + SWZ(wn + f * 16 + lr, cb));
            }
#pragma unroll
            for (int fm = 0; fm < 4; ++fm)
#pragma unroll
                for (int fn = 0; fn < 4; ++fn)
                    acc[fm][fn] = __builtin_amdgcn_mfma_f32_16x16x32_bf16(ah[fm], bh[fn], acc[fm][fn], 0, 0, 0);
        }
        __syncthreads();
    }

#pragma unroll
    for (int fn = 0; fn < 4; ++fn) {
        const int col = n0 + wn + fn * 16 + lr;
        const float bv = bias[col];
#pragma unroll
        for (int fm = 0; fm < 4; ++fm) {
            const int row0 = m0 + wm + fm * 16 + lk * 4;
            if constexpr (EPI == 1) {
#pragma unroll
                for (int r = 0; r < 4; ++r)
                    Ch[(size_t)(row0 + r) * N + col] = f2bf(acc[fm][fn][r] + bv);
            } else if constexpr (EPI == 3) {
#pragma unroll
                for (int r = 0; r < 4; ++r)
                    Ch[(size_t)(row0 + r) * N + col] = f2bf((acc[fm][fn][r] + bv) * 0.18033688011112042f);
            } else {
                unsigned short h4[4];
#pragma unroll
                for (int r = 0; r < 4; ++r)
                    h4[r] = f2bf(acc[fm][fn][r] + bv);
                size_t o = (((size_t)((row0 >> 10) * NH + (col >> 6)) * 64 + (col & 63)) << 10) + (row0 & 1023);
                *reinterpret_cast<uint2*>(&Ch[o]) = *reinterpret_cast<uint2*>(h4);
            }
        }
    }
}

// ---------------------------------------------------------------------------
// Stage one 128-row x 64-col plane tile (gemm2).
// ---------------------------------------------------------------------------
__device__ __forceinline__ void stageplane(const unsigned short* g0, int Kstride,
                                           unsigned short* l0, int lane)
{
#pragma unroll
    for (int r = 0; r < 16; ++r) {
        int row  = r * 8 + (lane >> 3);
        int colb = ((lane & 7) << 4) ^ ((row & 7) << 4);
        const unsigned short* src = g0 + (size_t)row * Kstride + (colb >> 1);
        __builtin_amdgcn_global_load_lds((gptr_t)src, (lptr_t)(l0 + r * 512), 16, 0, 0);
    }
}

// ---------------------------------------------------------------------------
// Split-bf16 MFMA GEMM (3 products) — O-projection, fp32 out.
// ---------------------------------------------------------------------------
__global__ __launch_bounds__(256, 2) void gemm2(const unsigned short* __restrict__ Ah,
                                                const unsigned short* __restrict__ Al,
                                                const unsigned short* __restrict__ Bht,
                                                const unsigned short* __restrict__ Blt,
                                                const float* __restrict__ bias,
                                                float* __restrict__ C,
                                                int M, int N, int K)
{
    __shared__ unsigned short As_h[128 * 64], As_l[128 * 64];
    __shared__ unsigned short Bs_h[128 * 64], Bs_l[128 * 64];

    const int nbx = N >> 7;
    const int nwg = gridDim.x;
    const int qq  = nwg >> 3;
    const int id  = blockIdx.x;
    const int swz = (id & 7) * qq + (id >> 3);
    const int bx = swz % nbx, by = swz / nbx;
    const int m0 = by * 128, n0 = bx * 128;

    const int tid  = threadIdx.x;
    const int lane = tid & 63;
    const int w    = tid >> 6;
    const int wm = (w & 1) * 64;
    const int wn = (w >> 1) * 64;
    const int lr = lane & 15;
    const int lk = lane >> 4;

    f32x4 acc[4][4];
#pragma unroll
    for (int i = 0; i < 4; ++i)
#pragma unroll
        for (int j = 0; j < 4; ++j) acc[i][j] = (f32x4)(0.f);

    const unsigned short* mysrc =
        (w == 0) ? Ah + (size_t)m0 * K :
        (w == 1) ? Al + (size_t)m0 * K :
        (w == 2) ? Bht + (size_t)n0 * K :
                   Blt + (size_t)n0 * K;
    unsigned short* myplane =
        (w == 0) ? As_h : (w == 1) ? As_l : (w == 2) ? Bs_h : Bs_l;

    const int nt = K >> 6;
    for (int t = 0; t < nt; ++t) {
        stageplane(mysrc + ((size_t)t << 6), K, myplane, lane);
        __syncthreads();

#pragma unroll
        for (int ks = 0; ks < 2; ++ks) {
            bf16x8 ah[4], al[4], bh[4], bl[4];
            const int cb = ks * 64 + lk * 16;
#pragma unroll
            for (int f = 0; f < 4; ++f) {
                int rowA = wm + f * 16 + lr;
                ah[f] = *reinterpret_cast<const bf16x8*>((char*)As_h + SWZ(rowA, cb));
                al[f] = *reinterpret_cast<const bf16x8*>((char*)As_l + SWZ(rowA, cb));
                int rowB = wn + f * 16 + lr;
                bh[f] = *reinterpret_cast<const bf16x8*>((char*)Bs_h + SWZ(rowB, cb));
                bl[f] = *reinterpret_cast<const bf16x8*>((char*)Bs_l + SWZ(rowB, cb));
            }
#pragma unroll
            for (int fm = 0; fm < 4; ++fm)
#pragma unroll
                for (int fn = 0; fn < 4; ++fn) {
                    acc[fm][fn] = __builtin_amdgcn_mfma_f32_16x16x32_bf16(ah[fm], bh[fn], acc[fm][fn], 0, 0, 0);
                    acc[fm][fn] = __builtin_amdgcn_mfma_f32_16x16x32_bf16(ah[fm], bl[fn], acc[fm][fn], 0, 0, 0);
                    acc[fm][fn] = __builtin_amdgcn_mfma_f32_16x16x32_bf16(al[fm], bh[fn], acc[fm][fn], 0, 0, 0);
                }
        }
        __syncthreads();
    }

#pragma unroll
    for (int fn = 0; fn < 4; ++fn) {
        const int col = n0 + wn + fn * 16 + lr;
        const float bv = bias[col];
#pragma unroll
        for (int fm = 0; fm < 4; ++fm) {
            const int row0 = m0 + wm + fm * 16 + lk * 4;
#pragma unroll
            for (int r = 0; r < 4; ++r)
                C[(size_t)(row0 + r) * N + col] = acc[fm][fn][r] + bv;
        }
    }
}

// ---------------------------------------------------------------------------
// Stage 32 rows x 128B (row stride 1024 elems), pre-swizzled source.
// ---------------------------------------------------------------------------
__device__ __forceinline__ void stage32(const unsigned short* g0, unsigned short* l0, int lane)
{
#pragma unroll
    for (int r = 0; r < 4; ++r) {
        int row  = r * 8 + (lane >> 3);
        int colb = ((lane & 7) << 4) ^ ((row & 7) << 4);
        const unsigned short* src = g0 + ((size_t)row << 10) + (colb >> 1);
        __builtin_amdgcn_global_load_lds((gptr_t)src, (lptr_t)(l0 + r * 512), 16, 0, 0);
    }
}

// ---------------------------------------------------------------------------
// MFMA flash attention, SWAPPED operands: S^T = mfma(K, Q) so each lane's 16
// scores all belong to q-row (lane&15) -> softmax row-reduce = in-lane ops +
// 2 shfl_xor (vs 32). PV swapped too: ctx^T = mfma(Vt, P^T) with identical
// K/V LDS reads. exp2-domain (Q pre-scaled by 0.125*log2e). 40KB LDS.
// ---------------------------------------------------------------------------
__global__ __launch_bounds__(256, 4) void attn_mfma(const unsigned short* __restrict__ Qh,
                                                    const unsigned short* __restrict__ Kh,
                                                    const unsigned short* __restrict__ Vth,
                                                    unsigned short* __restrict__ Ch,
                                                    unsigned short* __restrict__ Cl)
{
    const int id  = blockIdx.x;
    const int qt  = (id >> 3) & 7;
    const int grp = (id & 7) | ((id >> 6) << 3);
    const int h = grp & 15, b = grp >> 4;

    const int tid  = threadIdx.x;
    const int lane = tid & 63;
    const int w    = tid >> 6;
    const int lr   = lane & 15;
    const int lk   = lane >> 4;

    __shared__ unsigned short KVs[2][2][4096];
    __shared__ unsigned short Ps[4][1024];   // per-wave P [16 q][64 key], SWZ'd

    // Q fragments (exp2-scaled bf16), q-row w*16 + lr (serves as B operand)
    bf16x8 qb[2];
    {
        const unsigned short* qrow = &Qh[(size_t)(b * LQ + qt * 64 + w * 16 + lr) * EMB + h * DH];
        qb[0] = *reinterpret_cast<const bf16x8*>(qrow + lk * 8);
        qb[1] = *reinterpret_cast<const bf16x8*>(qrow + 32 + lk * 8);
    }

    const unsigned short* K0 = Kh + ((size_t)(b * LK) << 10) + h * DH;
    const unsigned short* V0 = Vth + ((size_t)(grp * 64) << 10);

    {
        const int half = (w & 1) * 32;
        if (w < 2) stage32(K0 + ((size_t)half << 10), KVs[0][0] + half * 64, lane);
        else       stage32(V0 + ((size_t)half << 10), KVs[0][1] + half * 64, lane);
    }

    float m = -1e30f, lsum = 0.f;
    f32x4 acc[4];   // ctx^T: dv = f*16 + lk*4 + r, q-col = lr
#pragma unroll
    for (int f = 0; f < 4; ++f) acc[f] = (f32x4)(0.f);

    for (int kt = 0; kt < LK / 64; ++kt) {
        const int cur = kt & 1;
        __syncthreads();

        if (kt + 1 < LK / 64) {
            const size_t koff = (size_t)(kt + 1) * 64;
            const int half = (w & 1) * 32;
            if (w < 2) stage32(K0 + ((koff + half) << 10), KVs[cur ^ 1][0] + half * 64, lane);
            else       stage32(V0 + ((size_t)half << 10) + koff, KVs[cur ^ 1][1] + half * 64, lane);
        }

        const char* Ks = (const char*)KVs[cur][0];
        const char* Vs = (const char*)KVs[cur][1];

        // QK^T swapped: s[fn][r] = S[key = fn*16 + lk*4 + r][q = lr]
        f32x4 s[4];
#pragma unroll
        for (int fn = 0; fn < 4; ++fn) s[fn] = (f32x4)(0.f);
#pragma unroll
        for (int ks = 0; ks < 2; ++ks) {
            const int cb = ks * 64 + lk * 16;
#pragma unroll
            for (int fn = 0; fn < 4; ++fn) {
                bf16x8 kb = *reinterpret_cast<const bf16x8*>(Ks + SWZ(fn * 16 + lr, cb));
                s[fn] = __builtin_amdgcn_mfma_f32_16x16x32_bf16(kb, qb[ks], s[fn], 0, 0, 0);
            }
        }

        // softmax: per-lane row q = lr; combine 4 lane-groups via 2 shfl
        {
            f32x4 t4 = s[0];
#pragma unroll
            for (int fn = 1; fn < 4; ++fn)
#pragma unroll
                for (int r = 0; r < 4; ++r) t4[r] = fmaxf(t4[r], s[fn][r]);
            float mx = fmaxf(fmaxf(t4[0], t4[1]), fmaxf(t4[2], t4[3]));
            mx = fmaxf(mx, __shfl_xor(mx, 16));
            mx = fmaxf(mx, __shfl_xor(mx, 32));
            float mnew = fmaxf(m, mx);
            float corr = fexp2(m - mnew);
            m = mnew;
            float rs = 0.f;
#pragma unroll
            for (int fn = 0; fn < 4; ++fn)
#pragma unroll
                for (int r = 0; r < 4; ++r) {
                    float p = fexp2(s[fn][r] - mnew);
                    s[fn][r] = p;
                    rs += p;
                }
            rs += __shfl_xor(rs, 16);
            rs += __shfl_xor(rs, 32);
            lsum = lsum * corr + rs;
#pragma unroll
            for (int f = 0; f < 4; ++f)
#pragma unroll
                for (int r = 0; r < 4; ++r) acc[f][r] *= corr;
        }

        // P -> Ps[w]: row q=lr, packed b64 per key-block fn (keys lk*4+0..3)
#pragma unroll
        for (int fn = 0; fn < 4; ++fn) {
            uint2 pk;
            pk.x = (unsigned int)f2bf(s[fn][0]) | ((unsigned int)f2bf(s[fn][1]) << 16);
            pk.y = (unsigned int)f2bf(s[fn][2]) | ((unsigned int)f2bf(s[fn][3]) << 16);
            *reinterpret_cast<uint2*>((char*)Ps[w] + SWZ(lr, fn * 32 + lk * 8)) = pk;
        }

        // PV swapped: acc[f] += mfma(A = Vt block f, B = P^T)
#pragma unroll
        for (int ks = 0; ks < 2; ++ks) {
            const int cb = ks * 64 + lk * 16;
            bf16x8 pa = *reinterpret_cast<const bf16x8*>((char*)Ps[w] + SWZ(lr, cb));
#pragma unroll
            for (int f = 0; f < 4; ++f) {
                bf16x8 vb = *reinterpret_cast<const bf16x8*>(Vs + SWZ(f * 16 + lr, cb));
                acc[f] = __builtin_amdgcn_mfma_f32_16x16x32_bf16(vb, pa, acc[f], 0, 0, 0);
            }
        }
    }

    // epilogue: ctx^T -> ctx planes. dv = f*16 + lk*4 + r, q-row = w*16 + lr.
    {
        float inv = 1.f / lsum;
        const size_t row = (size_t)(b * LQ + qt * 64 + w * 16 + lr);
#pragma unroll
        for (int f = 0; f < 4; ++f)
#pragma unroll
            for (int r = 0; r < 4; ++r) {
                float x = acc[f][r] * inv;
                unsigned short hh = f2bf(x);
                size_t o = (row << 10) + h * DH + f * 16 + lk * 4 + r;
                Ch[o] = hh;
                Cl[o] = f2bf(x - bf2f(hh));
            }
    }
}

extern "C" void kernel_launch(void* const* d_in, const int* in_sizes, int n_in,
                              void* d_out, int out_size, void* d_ws, size_t ws_size,
                              hipStream_t stream)
{
    const float* query = (const float*)d_in[0];
    const float* key   = (const float*)d_in[1];
    const float* value = (const float*)d_in[2];
    const float* Wq = (const float*)d_in[3];
    const float* bq = (const float*)d_in[4];
    const float* Wk = (const float*)d_in[5];
    const float* bk = (const float*)d_in[6];
    const float* Wv = (const float*)d_in[7];
    const float* bv = (const float*)d_in[8];
    const float* Wo = (const float*)d_in[9];
    const float* bo = (const float*)d_in[10];
    float* out = (float*)d_out;

    // ws (88MB): Qh8 | Kh16 | Vth16 | Aq8 | Ak8 | Av8 | Ch8 | Cl8 | W planes 8
    unsigned short* Qh  = (unsigned short*)d_ws;
    unsigned short* Kh  = Qh  + (size_t)4194304;
    unsigned short* Vth = Kh  + (size_t)8388608;
    unsigned short* Aq  = Vth + (size_t)8388608;
    unsigned short* Ak  = Aq  + (size_t)4194304;
    unsigned short* Av  = Ak  + (size_t)4194304;
    unsigned short* Ch  = Av  + (size_t)4194304;
    unsigned short* Cl  = Ch  + (size_t)4194304;
    unsigned short* Wqt = Cl  + (size_t)4194304;
    unsigned short* Wkt = Wqt + (size_t)1048576;
    unsigned short* Wvt = Wkt + (size_t)524288;
    unsigned short* Woh = Wvt + (size_t)524288;
    unsigned short* Wol = Woh + (size_t)1048576;

    // Input + weight conversion (merged launches)
    asplit3<<<12288, 256, 0, stream>>>(query, key, value, Aq, Ak, Av);
    wsplit_all<<<3072, dim3(32, 8), 0, stream>>>(Wq, Wk, Wv, Wo, Wqt, Wkt, Wvt, Woh, Wol);

    // Projections
    gemm1<3><<<(EMB / 128) * (BB * LQ / 128), 256, 0, stream>>>(Aq, Wqt, bq, Qh, BB * LQ, EMB, EMB);
    gemm1<1><<<(EMB / 128) * (BB * LK / 128), 256, 0, stream>>>(Ak, Wkt, bk, Kh, BB * LK, EMB, VIN);
    gemm1<2><<<(VOUT / 128) * (BB * LK / 128), 256, 0, stream>>>(Av, Wvt, bv, Vth, BB * LK, VOUT, VIN);

    // Attention -> ctx split planes
    attn_mfma<<<LQ / 64 * NH * BB, 256, 0, stream>>>(Qh, Kh, Vth, Ch, Cl);

    // Output projection (3-product split, fp32-grade)
    gemm2<<<(EMB / 128) * (BB * LQ / 128), 256, 0, stream>>>(Ch, Cl, Woh, Wol, bo, out, BB * LQ, EMB, VOUT);
}

// Round 11
// 138.248 us; speedup vs baseline: 2.9433x; 1.0661x over previous
//
#include <hip/hip_runtime.h>

#define EMB  1024
#define VIN  512
#define VOUT 1024
#define NH   16
#define DH   64
#define BB   8
#define LQ   512
#define LK   1024

typedef __attribute__((ext_vector_type(8))) short bf16x8;
typedef __attribute__((ext_vector_type(4))) float f32x4;

typedef const __attribute__((address_space(1))) unsigned int* gptr_t;
typedef __attribute__((address_space(3))) unsigned int* lptr_t;

__device__ __forceinline__ unsigned short f2bf(float x) {
    unsigned int u = __float_as_uint(x);
    u += 0x7FFF + ((u >> 16) & 1);   // RN-even
    return (unsigned short)(u >> 16);
}
__device__ __forceinline__ float bf2f(unsigned short h) {
    return __uint_as_float(((unsigned int)h) << 16);
}
__device__ __forceinline__ float fexp2(float x) {
    return __builtin_amdgcn_exp2f(x);   // v_exp_f32 (base-2 native)
}

#define SWZ(row, cb) (((row) << 7) + ((cb) ^ (((row) & 7) << 4)))

// ---------------------------------------------------------------------------
// Merged elementwise fp32 -> bf16 hi plane for query/key/value.
// ---------------------------------------------------------------------------
__global__ __launch_bounds__(256) void asplit3(const float* __restrict__ q,
                                               const float* __restrict__ k,
                                               const float* __restrict__ v,
                                               unsigned short* __restrict__ Aq,
                                               unsigned short* __restrict__ Ak,
                                               unsigned short* __restrict__ Av)
{
    const int which = blockIdx.x >> 12;
    const float* in = (which == 0) ? q : (which == 1) ? k : v;
    unsigned short* out = (which == 0) ? Aq : (which == 1) ? Ak : Av;
    const int i = (blockIdx.x & 4095) * 256 + threadIdx.x;
    float val[4];
    *reinterpret_cast<float4*>(val) = *reinterpret_cast<const float4*>(&in[(size_t)i * 4]);
    unsigned short h[4];
#pragma unroll
    for (int j = 0; j < 4; ++j) h[j] = f2bf(val[j]);
    *reinterpret_cast<uint2*>(&out[(size_t)i * 4]) = *reinterpret_cast<uint2*>(h);
}

// ---------------------------------------------------------------------------
// Merged weight transpose-split: Wq,Wk,Wv -> hi planes; Wo -> hi+lo planes.
// ---------------------------------------------------------------------------
__device__ __forceinline__ void wtile(const float* W, unsigned short* Wht,
                                      unsigned short* Wlt, int K, int N,
                                      int bx, int by, int tx, int ty)
{
    __shared__ float t[32][33];
    const int n0 = bx * 32, k0 = by * 32;
#pragma unroll
    for (int r = 0; r < 32; r += 8)
        t[ty + r][tx] = W[(size_t)(k0 + ty + r) * N + n0 + tx];
    __syncthreads();
#pragma unroll
    for (int r = 0; r < 32; r += 8) {
        float x = t[tx][ty + r];
        unsigned short h = f2bf(x);
        size_t o = (size_t)(n0 + ty + r) * K + k0 + tx;
        Wht[o] = h;
        if (Wlt) Wlt[o] = f2bf(x - bf2f(h));
    }
}

__global__ __launch_bounds__(256) void wsplit_all(const float* __restrict__ Wq,
                                                  const float* __restrict__ Wk,
                                                  const float* __restrict__ Wv,
                                                  const float* __restrict__ Wo,
                                                  unsigned short* __restrict__ Wqt,
                                                  unsigned short* __restrict__ Wkt,
                                                  unsigned short* __restrict__ Wvt,
                                                  unsigned short* __restrict__ Woh,
                                                  unsigned short* __restrict__ Wol)
{
    const int id = blockIdx.x;
    const int tx = threadIdx.x, ty = threadIdx.y;
    if (id < 1024)       wtile(Wq, Wqt, nullptr, 1024, 1024, id & 31, id >> 5, tx, ty);
    else if (id < 1536)  wtile(Wk, Wkt, nullptr, 512, 1024, (id - 1024) & 31, (id - 1024) >> 5, tx, ty);
    else if (id < 2048)  wtile(Wv, Wvt, nullptr, 512, 1024, (id - 1536) & 31, (id - 1536) >> 5, tx, ty);
    else                 wtile(Wo, Woh, Wol, 1024, 1024, (id - 2048) & 31, (id - 2048) >> 5, tx, ty);
}

// ---------------------------------------------------------------------------
// Stage 64 rows x 64 cols of a bf16 plane into linear LDS (pre-swizzled src).
// ---------------------------------------------------------------------------
__device__ __forceinline__ void stagehalf(const unsigned short* g0, int Kstride,
                                          unsigned short* l0, int lane)
{
#pragma unroll
    for (int r = 0; r < 8; ++r) {
        int row  = r * 8 + (lane >> 3);
        int colb = ((lane & 7) << 4) ^ ((row & 7) << 4);
        const unsigned short* src = g0 + (size_t)row * Kstride + (colb >> 1);
        __builtin_amdgcn_global_load_lds((gptr_t)src, (lptr_t)(l0 + r * 512), 16, 0, 0);
    }
}

// ---------------------------------------------------------------------------
// Plain-bf16 MFMA GEMM (1 product), DOUBLE-BUFFERED LDS (prefetch after
// barrier flies during compute). EPI=1 natural, EPI=2 per-head transposed,
// EPI=3 natural scaled by 0.125*log2(e).
// ---------------------------------------------------------------------------
template<int EPI>
__global__ __launch_bounds__(256, 2) void gemm1(const unsigned short* __restrict__ Ah,
                                                const unsigned short* __restrict__ Bht,
                                                const float* __restrict__ bias,
                                                unsigned short* __restrict__ Ch,
                                                int M, int N, int K)
{
    __shared__ unsigned short As[2][128 * 64], Bs[2][128 * 64];

    const int nbx = N >> 7;
    const int nwg = gridDim.x;
    const int qq  = nwg >> 3;
    const int id  = blockIdx.x;
    const int swz = (id & 7) * qq + (id >> 3);
    const int bx = swz % nbx, by = swz / nbx;
    const int m0 = by * 128, n0 = bx * 128;

    const int tid  = threadIdx.x;
    const int lane = tid & 63;
    const int w    = tid >> 6;
    const int wm = (w & 1) * 64;
    const int wn = (w >> 1) * 64;
    const int lr = lane & 15;
    const int lk = lane >> 4;

    f32x4 acc[4][4];
#pragma unroll
    for (int i = 0; i < 4; ++i)
#pragma unroll
        for (int j = 0; j < 4; ++j) acc[i][j] = (f32x4)(0.f);

    const unsigned short* mysrc = (w < 2)
        ? Ah  + (size_t)(m0 + (w & 1) * 64) * K
        : Bht + (size_t)(n0 + (w & 1) * 64) * K;
    const int lofs = (w & 1) * 4096;
    unsigned short* pl0 = ((w < 2) ? As[0] : Bs[0]) + lofs;
    unsigned short* pl1 = ((w < 2) ? As[1] : Bs[1]) + lofs;

    stagehalf(mysrc, K, pl0, lane);

    const int nt = K >> 6;
    for (int t = 0; t < nt; ++t) {
        __syncthreads();   // drains vmcnt: buf[t&1] resident; prev reads done
        if (t + 1 < nt)
            stagehalf(mysrc + ((size_t)(t + 1) << 6), K, ((t & 1) ? pl0 : pl1), lane);

        const char* Ac = (const char*)As[t & 1];
        const char* Bc = (const char*)Bs[t & 1];
#pragma unroll
        for (int ks = 0; ks < 2; ++ks) {
            bf16x8 ah[4], bh[4];
            const int cb = ks * 64 + lk * 16;
#pragma unroll
            for (int f = 0; f < 4; ++f) {
                ah[f] = *reinterpret_cast<const bf16x8*>(Ac + SWZ(wm + f * 16 + lr, cb));
                bh[f] = *reinterpret_cast<const bf16x8*>(Bc + SWZ(wn + f * 16 + lr, cb));
            }
#pragma unroll
            for (int fm = 0; fm < 4; ++fm)
#pragma unroll
                for (int fn = 0; fn < 4; ++fn)
                    acc[fm][fn] = __builtin_amdgcn_mfma_f32_16x16x32_bf16(ah[fm], bh[fn], acc[fm][fn], 0, 0, 0);
        }
    }

#pragma unroll
    for (int fn = 0; fn < 4; ++fn) {
        const int col = n0 + wn + fn * 16 + lr;
        const float bv = bias[col];
#pragma unroll
        for (int fm = 0; fm < 4; ++fm) {
            const int row0 = m0 + wm + fm * 16 + lk * 4;
            if constexpr (EPI == 1) {
#pragma unroll
                for (int r = 0; r < 4; ++r)
                    Ch[(size_t)(row0 + r) * N + col] = f2bf(acc[fm][fn][r] + bv);
            } else if constexpr (EPI == 3) {
#pragma unroll
                for (int r = 0; r < 4; ++r)
                    Ch[(size_t)(row0 + r) * N + col] = f2bf((acc[fm][fn][r] + bv) * 0.18033688011112042f);
            } else {
                unsigned short h4[4];
#pragma unroll
                for (int r = 0; r < 4; ++r)
                    h4[r] = f2bf(acc[fm][fn][r] + bv);
                size_t o = (((size_t)((row0 >> 10) * NH + (col >> 6)) * 64 + (col & 63)) << 10) + (row0 & 1023);
                *reinterpret_cast<uint2*>(&Ch[o]) = *reinterpret_cast<uint2*>(h4);
            }
        }
    }
}

// ---------------------------------------------------------------------------
// Stage one 128-row x 64-col plane tile (gemm2).
// ---------------------------------------------------------------------------
__device__ __forceinline__ void stageplane(const unsigned short* g0, int Kstride,
                                           unsigned short* l0, int lane)
{
#pragma unroll
    for (int r = 0; r < 16; ++r) {
        int row  = r * 8 + (lane >> 3);
        int colb = ((lane & 7) << 4) ^ ((row & 7) << 4);
        const unsigned short* src = g0 + (size_t)row * Kstride + (colb >> 1);
        __builtin_amdgcn_global_load_lds((gptr_t)src, (lptr_t)(l0 + r * 512), 16, 0, 0);
    }
}

// ---------------------------------------------------------------------------
// Split-bf16 MFMA GEMM (3 products) — O-projection, fp32 out, double-buffered.
// 128KB LDS, 1 block/CU (grid is 1/CU anyway).
// ---------------------------------------------------------------------------
__global__ __launch_bounds__(256) void gemm2(const unsigned short* __restrict__ Ah,
                                             const unsigned short* __restrict__ Al,
                                             const unsigned short* __restrict__ Bht,
                                             const unsigned short* __restrict__ Blt,
                                             const float* __restrict__ bias,
                                             float* __restrict__ C,
                                             int M, int N, int K)
{
    __shared__ unsigned short As_h[2][128 * 64], As_l[2][128 * 64];
    __shared__ unsigned short Bs_h[2][128 * 64], Bs_l[2][128 * 64];

    const int nbx = N >> 7;
    const int nwg = gridDim.x;
    const int qq  = nwg >> 3;
    const int id  = blockIdx.x;
    const int swz = (id & 7) * qq + (id >> 3);
    const int bx = swz % nbx, by = swz / nbx;
    const int m0 = by * 128, n0 = bx * 128;

    const int tid  = threadIdx.x;
    const int lane = tid & 63;
    const int w    = tid >> 6;
    const int wm = (w & 1) * 64;
    const int wn = (w >> 1) * 64;
    const int lr = lane & 15;
    const int lk = lane >> 4;

    f32x4 acc[4][4];
#pragma unroll
    for (int i = 0; i < 4; ++i)
#pragma unroll
        for (int j = 0; j < 4; ++j) acc[i][j] = (f32x4)(0.f);

    const unsigned short* mysrc =
        (w == 0) ? Ah + (size_t)m0 * K :
        (w == 1) ? Al + (size_t)m0 * K :
        (w == 2) ? Bht + (size_t)n0 * K :
                   Blt + (size_t)n0 * K;
    unsigned short* pl0 = (w == 0) ? As_h[0] : (w == 1) ? As_l[0] : (w == 2) ? Bs_h[0] : Bs_l[0];
    unsigned short* pl1 = (w == 0) ? As_h[1] : (w == 1) ? As_l[1] : (w == 2) ? Bs_h[1] : Bs_l[1];

    stageplane(mysrc, K, pl0, lane);

    const int nt = K >> 6;
    for (int t = 0; t < nt; ++t) {
        __syncthreads();
        if (t + 1 < nt)
            stageplane(mysrc + ((size_t)(t + 1) << 6), K, ((t & 1) ? pl0 : pl1), lane);

        const char* Ahc = (const char*)As_h[t & 1];
        const char* Alc = (const char*)As_l[t & 1];
        const char* Bhc = (const char*)Bs_h[t & 1];
        const char* Blc = (const char*)Bs_l[t & 1];
#pragma unroll
        for (int ks = 0; ks < 2; ++ks) {
            bf16x8 ah[4], al[4], bh[4], bl[4];
            const int cb = ks * 64 + lk * 16;
#pragma unroll
            for (int f = 0; f < 4; ++f) {
                int rowA = wm + f * 16 + lr;
                ah[f] = *reinterpret_cast<const bf16x8*>(Ahc + SWZ(rowA, cb));
                al[f] = *reinterpret_cast<const bf16x8*>(Alc + SWZ(rowA, cb));
                int rowB = wn + f * 16 + lr;
                bh[f] = *reinterpret_cast<const bf16x8*>(Bhc + SWZ(rowB, cb));
                bl[f] = *reinterpret_cast<const bf16x8*>(Blc + SWZ(rowB, cb));
            }
#pragma unroll
            for (int fm = 0; fm < 4; ++fm)
#pragma unroll
                for (int fn = 0; fn < 4; ++fn) {
                    acc[fm][fn] = __builtin_amdgcn_mfma_f32_16x16x32_bf16(ah[fm], bh[fn], acc[fm][fn], 0, 0, 0);
                    acc[fm][fn] = __builtin_amdgcn_mfma_f32_16x16x32_bf16(ah[fm], bl[fn], acc[fm][fn], 0, 0, 0);
                    acc[fm][fn] = __builtin_amdgcn_mfma_f32_16x16x32_bf16(al[fm], bh[fn], acc[fm][fn], 0, 0, 0);
                }
        }
    }

#pragma unroll
    for (int fn = 0; fn < 4; ++fn) {
        const int col = n0 + wn + fn * 16 + lr;
        const float bv = bias[col];
#pragma unroll
        for (int fm = 0; fm < 4; ++fm) {
            const int row0 = m0 + wm + fm * 16 + lk * 4;
#pragma unroll
            for (int r = 0; r < 4; ++r)
                C[(size_t)(row0 + r) * N + col] = acc[fm][fn][r] + bv;
        }
    }
}

// ---------------------------------------------------------------------------
// Stage 32 rows x 128B (row stride 1024 elems), pre-swizzled source.
// ---------------------------------------------------------------------------
__device__ __forceinline__ void stage32(const unsigned short* g0, unsigned short* l0, int lane)
{
#pragma unroll
    for (int r = 0; r < 4; ++r) {
        int row  = r * 8 + (lane >> 3);
        int colb = ((lane & 7) << 4) ^ ((row & 7) << 4);
        const unsigned short* src = g0 + ((size_t)row << 10) + (colb >> 1);
        __builtin_amdgcn_global_load_lds((gptr_t)src, (lptr_t)(l0 + r * 512), 16, 0, 0);
    }
}

// ---------------------------------------------------------------------------
// MFMA flash attention, swapped operands, QBLK=128: each block covers 128
// q-rows; each wave owns 32 (2 fragments) so every K/V LDS read feeds 2 MFMAs
// (LDS-pipe was the bottleneck). exp2-domain softmax, lane-local rows.
// 48KB LDS. Grid 512, same-XCD grouping per (b,h).
// ---------------------------------------------------------------------------
__global__ __launch_bounds__(256, 2) void attn_mfma(const unsigned short* __restrict__ Qh,
                                                    const unsigned short* __restrict__ Kh,
                                                    const unsigned short* __restrict__ Vth,
                                                    unsigned short* __restrict__ Ch,
                                                    unsigned short* __restrict__ Cl)
{
    const int id  = blockIdx.x;
    const int qt  = (id >> 3) & 3;                 // 4 q-blocks of 128
    const int grp = (id & 7) | ((id >> 5) << 3);   // 0..127, same-XCD groups
    const int h = grp & 15, b = grp >> 4;

    const int tid  = threadIdx.x;
    const int lane = tid & 63;
    const int w    = tid >> 6;
    const int lr   = lane & 15;
    const int lk   = lane >> 4;

    __shared__ unsigned short KVs[2][2][4096];   // [buf][K,Vt][64x64]
    __shared__ unsigned short Ps[4][2048];       // per-wave P [32 q][64 key]

    // Q fragments (exp2-scaled bf16): qf=0/1, q-row qt*128 + w*32 + qf*16 + lr
    bf16x8 qb[2][2];
#pragma unroll
    for (int qf = 0; qf < 2; ++qf) {
        const unsigned short* qrow =
            &Qh[(size_t)(b * LQ + qt * 128 + w * 32 + qf * 16 + lr) * EMB + h * DH];
        qb[qf][0] = *reinterpret_cast<const bf16x8*>(qrow + lk * 8);
        qb[qf][1] = *reinterpret_cast<const bf16x8*>(qrow + 32 + lk * 8);
    }

    const unsigned short* K0 = Kh + ((size_t)(b * LK) << 10) + h * DH;
    const unsigned short* V0 = Vth + ((size_t)(grp * 64) << 10);

    {
        const int half = (w & 1) * 32;
        if (w < 2) stage32(K0 + ((size_t)half << 10), KVs[0][0] + half * 64, lane);
        else       stage32(V0 + ((size_t)half << 10), KVs[0][1] + half * 64, lane);
    }

    float m[2] = {-1e30f, -1e30f}, lsum[2] = {0.f, 0.f};
    f32x4 acc[2][4];
#pragma unroll
    for (int qf = 0; qf < 2; ++qf)
#pragma unroll
        for (int f = 0; f < 4; ++f) acc[qf][f] = (f32x4)(0.f);

    for (int kt = 0; kt < LK / 64; ++kt) {
        const int cur = kt & 1;
        __syncthreads();

        if (kt + 1 < LK / 64) {
            const size_t koff = (size_t)(kt + 1) * 64;
            const int half = (w & 1) * 32;
            if (w < 2) stage32(K0 + ((koff + half) << 10), KVs[cur ^ 1][0] + half * 64, lane);
            else       stage32(V0 + ((size_t)half << 10) + koff, KVs[cur ^ 1][1] + half * 64, lane);
        }

        const char* Ks = (const char*)KVs[cur][0];
        const char* Vs = (const char*)KVs[cur][1];

        // QK^T swapped: each kb read feeds both q-fragments.
        f32x4 s[2][4];
#pragma unroll
        for (int qf = 0; qf < 2; ++qf)
#pragma unroll
            for (int fn = 0; fn < 4; ++fn) s[qf][fn] = (f32x4)(0.f);
#pragma unroll
        for (int ks = 0; ks < 2; ++ks) {
            const int cb = ks * 64 + lk * 16;
#pragma unroll
            for (int fn = 0; fn < 4; ++fn) {
                bf16x8 kb = *reinterpret_cast<const bf16x8*>(Ks + SWZ(fn * 16 + lr, cb));
                s[0][fn] = __builtin_amdgcn_mfma_f32_16x16x32_bf16(kb, qb[0][ks], s[0][fn], 0, 0, 0);
                s[1][fn] = __builtin_amdgcn_mfma_f32_16x16x32_bf16(kb, qb[1][ks], s[1][fn], 0, 0, 0);
            }
        }

        // softmax per q-fragment (lane-local row q = lr)
#pragma unroll
        for (int qf = 0; qf < 2; ++qf) {
            f32x4 t4 = s[qf][0];
#pragma unroll
            for (int fn = 1; fn < 4; ++fn)
#pragma unroll
                for (int r = 0; r < 4; ++r) t4[r] = fmaxf(t4[r], s[qf][fn][r]);
            float mx = fmaxf(fmaxf(t4[0], t4[1]), fmaxf(t4[2], t4[3]));
            mx = fmaxf(mx, __shfl_xor(mx, 16));
            mx = fmaxf(mx, __shfl_xor(mx, 32));
            float mnew = fmaxf(m[qf], mx);
            float corr = fexp2(m[qf] - mnew);
            m[qf] = mnew;
            float rs = 0.f;
#pragma unroll
            for (int fn = 0; fn < 4; ++fn)
#pragma unroll
                for (int r = 0; r < 4; ++r) {
                    float p = fexp2(s[qf][fn][r] - mnew);
                    s[qf][fn][r] = p;
                    rs += p;
                }
            rs += __shfl_xor(rs, 16);
            rs += __shfl_xor(rs, 32);
            lsum[qf] = lsum[qf] * corr + rs;
#pragma unroll
            for (int f = 0; f < 4; ++f)
#pragma unroll
                for (int r = 0; r < 4; ++r) acc[qf][f][r] *= corr;
        }

        // P -> Ps[w]: rows qf*16 + lr, packed b64 per key-block
#pragma unroll
        for (int qf = 0; qf < 2; ++qf)
#pragma unroll
            for (int fn = 0; fn < 4; ++fn) {
                uint2 pk;
                pk.x = (unsigned int)f2bf(s[qf][fn][0]) | ((unsigned int)f2bf(s[qf][fn][1]) << 16);
                pk.y = (unsigned int)f2bf(s[qf][fn][2]) | ((unsigned int)f2bf(s[qf][fn][3]) << 16);
                *reinterpret_cast<uint2*>((char*)Ps[w] + SWZ(qf * 16 + lr, fn * 32 + lk * 8)) = pk;
            }

        // PV swapped: each vb read feeds both q-fragments.
#pragma unroll
        for (int ks = 0; ks < 2; ++ks) {
            const int cb = ks * 64 + lk * 16;
            bf16x8 pa0 = *reinterpret_cast<const bf16x8*>((char*)Ps[w] + SWZ(lr, cb));
            bf16x8 pa1 = *reinterpret_cast<const bf16x8*>((char*)Ps[w] + SWZ(16 + lr, cb));
#pragma unroll
            for (int f = 0; f < 4; ++f) {
                bf16x8 vb = *reinterpret_cast<const bf16x8*>(Vs + SWZ(f * 16 + lr, cb));
                acc[0][f] = __builtin_amdgcn_mfma_f32_16x16x32_bf16(vb, pa0, acc[0][f], 0, 0, 0);
                acc[1][f] = __builtin_amdgcn_mfma_f32_16x16x32_bf16(vb, pa1, acc[1][f], 0, 0, 0);
            }
        }
    }

    // epilogue: ctx^T -> ctx planes. dv = f*16 + lk*4 + r, q-row per qf.
#pragma unroll
    for (int qf = 0; qf < 2; ++qf) {
        float inv = 1.f / lsum[qf];
        const size_t row = (size_t)(b * LQ + qt * 128 + w * 32 + qf * 16 + lr);
#pragma unroll
        for (int f = 0; f < 4; ++f)
#pragma unroll
            for (int r = 0; r < 4; ++r) {
                float x = acc[qf][f][r] * inv;
                unsigned short hh = f2bf(x);
                size_t o = (row << 10) + h * DH + f * 16 + lk * 4 + r;
                Ch[o] = hh;
                Cl[o] = f2bf(x - bf2f(hh));
            }
    }
}

extern "C" void kernel_launch(void* const* d_in, const int* in_sizes, int n_in,
                              void* d_out, int out_size, void* d_ws, size_t ws_size,
                              hipStream_t stream)
{
    const float* query = (const float*)d_in[0];
    const float* key   = (const float*)d_in[1];
    const float* value = (const float*)d_in[2];
    const float* Wq = (const float*)d_in[3];
    const float* bq = (const float*)d_in[4];
    const float* Wk = (const float*)d_in[5];
    const float* bk = (const float*)d_in[6];
    const float* Wv = (const float*)d_in[7];
    const float* bv = (const float*)d_in[8];
    const float* Wo = (const float*)d_in[9];
    const float* bo = (const float*)d_in[10];
    float* out = (float*)d_out;

    // ws (88MB): Qh8 | Kh16 | Vth16 | Aq8 | Ak8 | Av8 | Ch8 | Cl8 | W planes 8
    unsigned short* Qh  = (unsigned short*)d_ws;
    unsigned short* Kh  = Qh  + (size_t)4194304;
    unsigned short* Vth = Kh  + (size_t)8388608;
    unsigned short* Aq  = Vth + (size_t)8388608;
    unsigned short* Ak  = Aq  + (size_t)4194304;
    unsigned short* Av  = Ak  + (size_t)4194304;
    unsigned short* Ch  = Av  + (size_t)4194304;
    unsigned short* Cl  = Ch  + (size_t)4194304;
    unsigned short* Wqt = Cl  + (size_t)4194304;
    unsigned short* Wkt = Wqt + (size_t)1048576;
    unsigned short* Wvt = Wkt + (size_t)524288;
    unsigned short* Woh = Wvt + (size_t)524288;
    unsigned short* Wol = Woh + (size_t)1048576;

    // Input + weight conversion (merged launches)
    asplit3<<<12288, 256, 0, stream>>>(query, key, value, Aq, Ak, Av);
    wsplit_all<<<3072, dim3(32, 8), 0, stream>>>(Wq, Wk, Wv, Wo, Wqt, Wkt, Wvt, Woh, Wol);

    // Projections
    gemm1<3><<<(EMB / 128) * (BB * LQ / 128), 256, 0, stream>>>(Aq, Wqt, bq, Qh, BB * LQ, EMB, EMB);
    gemm1<1><<<(EMB / 128) * (BB * LK / 128), 256, 0, stream>>>(Ak, Wkt, bk, Kh, BB * LK, EMB, VIN);
    gemm1<2><<<(VOUT / 128) * (BB * LK / 128), 256, 0, stream>>>(Av, Wvt, bv, Vth, BB * LK, VOUT, VIN);

    // Attention -> ctx split planes
    attn_mfma<<<LQ / 128 * NH * BB, 256, 0, stream>>>(Qh, Kh, Vth, Ch, Cl);

    // Output projection (3-product split, fp32-grade)
    gemm2<<<(EMB / 128) * (BB * LQ / 128), 256, 0, stream>>>(Ch, Cl, Woh, Wol, bo, out, BB * LQ, EMB, VOUT);
}